// Round 2
// 330.806 us; speedup vs baseline: 1.5282x; 1.5282x over previous
//
#include <hip/hip_runtime.h>

// NeighborhoodAttention2D: B=8, C=512, H=W=56, heads=16, d=32, KSZ=7
// Round 10: identical to round 9 (bench infra failed twice; kernel re-audited
// clean — LDS bounds/alignment, MFMA layouts, mask indices all verified).
//  - one block per (b, h, 8x8 query tile); 49 tiles (56 = 7*8 exact)
//  - key union of an 8x8 tile is a 14x14 patch -> pad rows to 16 -> 224 keys
//  - QK^T swapped (A=K, B=Q): lane l15 = query, 14 MFMAs (d=32 = one K-step)
//  - softmax in-lane (56 vals) + 2 shfl_xor across quads
//  - P (bf16, normalized) -> per-wave LDS strip; PV: A=P, B=V^T, 14 MFMAs
// GEMM1/GEMM3 unchanged from green round-8.

typedef unsigned short ushort_t;
typedef short bf16x8 __attribute__((ext_vector_type(8)));      // 8 bf16 = 4 VGPRs (MFMA A/B frag)
typedef float f32x4 __attribute__((ext_vector_type(4)));       // MFMA C/D frag
typedef unsigned int uint4_t __attribute__((ext_vector_type(4)));
typedef unsigned int uint2_t __attribute__((ext_vector_type(2)));

#define BATCH 8
#define HEADS 16
#define HW 3136
#define HH 56
#define DD 32
#define CC 512
#define PLANE ((size_t)BATCH * HEADS * HW * DD)   // 12,845,056 elems per q/k/v plane
#define OUT_TOT ((size_t)BATCH * CC * HW)
#define LP 40                                      // GEMM LDS row pitch (elems); 80B rows

// attention tile geometry
#define KT 14                                      // key tiles (= patch rows)
#define KEYS 224                                   // 14 rows x 16 (14 valid + 2 pad)
#define KP 40                                      // Klds pitch (elems, 80B, 16B-aligned rows)
#define VPP 232                                    // Vlds/Plds pitch (elems, 464B, 16B-aligned rows)

__device__ __forceinline__ float bflo(unsigned int u) {
    union { unsigned int i; float f; } v; v.i = u << 16; return v.f;
}
__device__ __forceinline__ float bfhi(unsigned int u) {
    union { unsigned int i; float f; } v; v.i = u & 0xFFFF0000u; return v.f;
}
__device__ __forceinline__ ushort_t f2bf(float f) {
    union { float f; unsigned int i; } v; v.f = f;
    unsigned int r = v.i + 0x7FFFu + ((v.i >> 16) & 1u);   // RNE
    return (ushort_t)(r >> 16);
}
__device__ __forceinline__ unsigned int pack2(float a, float b) {
    return (unsigned int)f2bf(a) | ((unsigned int)f2bf(b) << 16);
}

__global__ __launch_bounds__(256) void zero_out_f32(float* __restrict__ out) {
    size_t idx = (size_t)blockIdx.x * 256 + threadIdx.x;
    if (idx < OUT_TOT) out[idx] = 0.f;
}

// ---------------- GEMM1: qkv^T = qkv_w (1536x512 f32) . x (f32, [b][k][pixel]) ----------
__global__ __launch_bounds__(256) void qkv_gemm_kernel(const float* __restrict__ x,
                                                       const float* __restrict__ w,
                                                       ushort_t* __restrict__ qkv) {
    __shared__ __align__(16) ushort_t lds_p[128 * LP];
    __shared__ __align__(16) ushort_t lds_q[64 * LP];
    const int K = CC;
    int tid = threadIdx.x;
    int b = blockIdx.z;
    int n0 = blockIdx.y * 128;
    int p0 = blockIdx.x * 64;
    int lane = tid & 63, wv = tid >> 6;
    int wp = wv & 1, wq = wv >> 1;
    int quad = lane >> 4, l15 = lane & 15;

    f32x4 acc[4][2];
    #pragma unroll
    for (int i = 0; i < 4; ++i)
        #pragma unroll
        for (int jq = 0; jq < 2; ++jq) acc[i][jq] = (f32x4){0.f, 0.f, 0.f, 0.f};

    int spx = tid & 63;
    int sk8 = (tid >> 6) * 8;

    for (int kt = 0; kt < K / 32; ++kt) {
        __syncthreads();
        #pragma unroll
        for (int r = 0; r < 2; ++r) {      // A (weights f32->bf16)
            int chunk = tid + r * 256;
            int row = chunk >> 2, k8 = (chunk & 3) * 8;
            const float* src = w + (size_t)(n0 + row) * K + kt * 32 + k8;
            float4 f0 = *(const float4*)src;
            float4 f1 = *(const float4*)(src + 4);
            uint4_t u;
            u[0] = pack2(f0.x, f0.y);
            u[1] = pack2(f0.z, f0.w);
            u[2] = pack2(f1.x, f1.y);
            u[3] = pack2(f1.z, f1.w);
            *(uint4_t*)&lds_p[row * LP + k8] = u;
        }
        {                                   // B (x f32 -> LDS [pixel][k])
            const float* xcol = x + ((size_t)b * CC + kt * 32 + sk8) * HW + p0 + spx;
            float v0 = xcol[0];
            float v1 = xcol[(size_t)HW];
            float v2 = xcol[(size_t)2 * HW];
            float v3 = xcol[(size_t)3 * HW];
            float v4 = xcol[(size_t)4 * HW];
            float v5 = xcol[(size_t)5 * HW];
            float v6 = xcol[(size_t)6 * HW];
            float v7 = xcol[(size_t)7 * HW];
            uint4_t u;
            u[0] = pack2(v0, v1);
            u[1] = pack2(v2, v3);
            u[2] = pack2(v4, v5);
            u[3] = pack2(v6, v7);
            *(uint4_t*)&lds_q[spx * LP + sk8] = u;
        }
        __syncthreads();
        bf16x8 afrag[4], bfrag[2];
        #pragma unroll
        for (int i = 0; i < 4; ++i)
            afrag[i] = *(const bf16x8*)&lds_p[(wp * 64 + i * 16 + l15) * LP + quad * 8];
        #pragma unroll
        for (int jq = 0; jq < 2; ++jq)
            bfrag[jq] = *(const bf16x8*)&lds_q[(wq * 32 + jq * 16 + l15) * LP + quad * 8];
        #pragma unroll
        for (int i = 0; i < 4; ++i)
            #pragma unroll
            for (int jq = 0; jq < 2; ++jq)
                acc[i][jq] = __builtin_amdgcn_mfma_f32_16x16x32_bf16(afrag[i], bfrag[jq],
                                                                     acc[i][jq], 0, 0, 0);
    }
    const float qscale = 0.17677669529663687f;   // 1/sqrt(32)
    #pragma unroll
    for (int i = 0; i < 4; ++i) {
        int nbase = n0 + wp * 64 + i * 16 + quad * 4;
        int which = nbase >> 9;
        int h = (nbase >> 5) & 15;
        int dch = nbase & 31;
        float sc = (which == 0) ? qscale : 1.0f;
        #pragma unroll
        for (int jq = 0; jq < 2; ++jq) {
            int pix = p0 + wq * 32 + jq * 16 + l15;
            uint2_t v;
            v[0] = pack2(acc[i][jq][0] * sc, acc[i][jq][1] * sc);
            v[1] = pack2(acc[i][jq][2] * sc, acc[i][jq][3] * sc);
            ushort_t* dst = qkv + (size_t)which * PLANE +
                            ((((size_t)b * HEADS + h) * HW + pix) * DD + dch);
            *(uint2_t*)dst = v;
        }
    }
}

// ---------------- MFMA attention: one block per (b, h, 8x8 query tile) ----------------
__global__ __launch_bounds__(256) void attn_mfma(ushort_t* __restrict__ qkv,
                                                 const float* __restrict__ rpb) {
    __shared__ __align__(16) ushort_t Klds[KEYS * KP];       // [kk][d]      17920 B
    __shared__ __align__(16) ushort_t Vlds[DD * VPP];        // [d][kk]      14848 B
    __shared__ __align__(16) ushort_t Plds[64 * VPP];        // [wave*16+q][kk] 29696 B
    __shared__ float rpbl[169];                              //               676 B

    int tid = threadIdx.x;
    int b = blockIdx.z, h = blockIdx.y;
    int tile = blockIdx.x;
    int ti = tile / 7, tj = tile - ti * 7;
    int i0 = ti * 8, j0 = tj * 8;
    int kr0 = min(max(i0 - 3, 0), HH - 14);
    int kc0 = min(max(j0 - 3, 0), HH - 14);

    const ushort_t* qp = qkv + (((size_t)b * HEADS + h) * HW) * DD;
    const ushort_t* kp = qp + PLANE;
    const ushort_t* vp = qp + 2 * PLANE;

    // ---- stage rpb slice for this head (13x13 f32)
    if (tid < 169) rpbl[tid] = rpb[h * 169 + tid];

    // ---- stage K patch: Klds[(u*16+w)][d]; zero pad cols w=14,15
    #pragma unroll
    for (int r = 0; r < 4; ++r) {
        int idx = tid + r * 256;
        if (idx < 784) {                       // 14 rows * 14 keys * 4 octets
            int u = idx / 56;
            int rem = idx - u * 56;
            int w = rem >> 2, d8 = (rem & 3) << 3;
            const ushort_t* src = kp + ((size_t)((kr0 + u) * HH + kc0 + w)) * DD + d8;
            *(uint4_t*)&Klds[(u * 16 + w) * KP + d8] = *(const uint4_t*)src;
        } else if (idx < 896) {                // zero 28 pad rows x 4 octets
            int z = idx - 784;
            int u = z >> 3, rem = z & 7;
            int w = 14 + (rem >> 2), d8 = (rem & 3) << 3;
            *(uint4_t*)&Klds[(u * 16 + w) * KP + d8] = (uint4_t){0, 0, 0, 0};
        }
    }
    // ---- stage V transposed: Vlds[d][kk]; zero pad cols kk%16 in {14,15}
    #pragma unroll
    for (int rr = 0; rr < 2; ++rr) {
        int idx = tid + rr * 256;
        if (idx < 448) {                       // 14 rows * 8 key-pairs * 4 octets
            int u = idx >> 5, rem = idx & 31;
            int pr = rem >> 2, d8 = (rem & 3) << 3;
            int kk0 = u * 16 + pr * 2;
            if (pr < 7) {
                const ushort_t* s0 = vp + ((size_t)((kr0 + u) * HH + kc0 + pr * 2)) * DD + d8;
                uint4_t a = *(const uint4_t*)s0;
                uint4_t c = *(const uint4_t*)(s0 + DD);
                #pragma unroll
                for (int e = 0; e < 4; ++e) {
                    unsigned lo = (a[e] & 0xFFFFu) | (c[e] << 16);
                    unsigned hi = (a[e] >> 16) | (c[e] & 0xFFFF0000u);
                    *(unsigned*)&Vlds[(d8 + 2 * e) * VPP + kk0] = lo;
                    *(unsigned*)&Vlds[(d8 + 2 * e + 1) * VPP + kk0] = hi;
                }
            } else {
                #pragma unroll
                for (int e = 0; e < 8; ++e)
                    *(unsigned*)&Vlds[(d8 + e) * VPP + kk0] = 0;
            }
        }
    }

    int lane = tid & 63, wv = tid >> 6;
    int l15 = lane & 15, quad = lane >> 4;
    int q_idx = wv * 16 + l15;                 // this lane's query (B-operand row)
    int qi = i0 + (q_idx >> 3), qj = j0 + (q_idx & 7);
    int si = min(max(qi - 3, 0), HH - 7);
    int sj = min(max(qj - 3, 0), HH - 7);

    // Q fragment straight from global (B operand: lane l15 = query, quad*8 = d octet)
    bf16x8 bq = *(const bf16x8*)(qp + ((size_t)(qi * HH + qj)) * DD + quad * 8);

    // per-lane column tables: key col w = quad*4 + r (constant across patch rows)
    int jbase = kc0 + quad * 4 - sj;           // col valid iff jbase + r in [0,6]
    int cbase = kc0 + quad * 4 - qj + 6;       // rpb col index = cbase + r
    int coff[4];
    bool cok[4];
    #pragma unroll
    for (int r2 = 0; r2 < 4; ++r2) {
        cok[r2] = (unsigned)(jbase + r2) <= 6u;
        coff[r2] = min(max(cbase + r2, 0), 12);
    }

    __syncthreads();

    // ---- QK^T: swapped operands (A=K, B=Q) -> lane holds logits of query l15,
    //      keys (t*16 + quad*4 + reg)
    f32x4 lg[KT];
    f32x4 zf = {0.f, 0.f, 0.f, 0.f};
    #pragma unroll
    for (int t = 0; t < KT; ++t) {
        bf16x8 ak = *(const bf16x8*)&Klds[(t * 16 + l15) * KP + quad * 8];
        lg[t] = __builtin_amdgcn_mfma_f32_16x16x32_bf16(ak, bq, zf, 0, 0, 0);
    }

    // ---- bias + neighborhood mask
    int abase = kr0 - qi + 6;                  // rpb row index = abase + t
    #pragma unroll
    for (int t = 0; t < KT; ++t) {
        bool rok = (unsigned)(kr0 + t - si) <= 6u;
        int arow = min(max(abase + t, 0), 12);
        const float* br = &rpbl[arow * 13];
        #pragma unroll
        for (int r2 = 0; r2 < 4; ++r2) {
            float bias = br[coff[r2]];
            lg[t][r2] = (rok && cok[r2]) ? lg[t][r2] + bias : -1e30f;
        }
    }

    // ---- softmax over 224 keys: in-lane (56) + quad reduce (xor 16, 32)
    float m = -1e30f;
    #pragma unroll
    for (int t = 0; t < KT; ++t)
        #pragma unroll
        for (int r2 = 0; r2 < 4; ++r2) m = fmaxf(m, lg[t][r2]);
    m = fmaxf(m, __shfl_xor(m, 16));
    m = fmaxf(m, __shfl_xor(m, 32));
    float s = 0.f;
    #pragma unroll
    for (int t = 0; t < KT; ++t)
        #pragma unroll
        for (int r2 = 0; r2 < 4; ++r2) {
            float e = __expf(lg[t][r2] - m);
            lg[t][r2] = e;
            s += e;
        }
    s += __shfl_xor(s, 16);
    s += __shfl_xor(s, 32);
    float inv = 1.f / s;

    // ---- P -> bf16 (normalized; lane's inv matches its query row l15) -> LDS
    ushort_t* pw = &Plds[(wv * 16 + l15) * VPP];
    #pragma unroll
    for (int t = 0; t < KT; ++t) {
        uint2_t u;
        u[0] = pack2(lg[t][0] * inv, lg[t][1] * inv);
        u[1] = pack2(lg[t][2] * inv, lg[t][3] * inv);
        *(uint2_t*)&pw[t * 16 + quad * 4] = u;
    }

    __syncthreads();   // P strips are per-wave private, but barrier is cheap insurance

    // ---- PV: A = P [query][key], B = V^T [d][key]; 7 K-steps x 2 d-tiles
    f32x4 acc0 = zf, acc1 = zf;
    const ushort_t* prow = &Plds[(wv * 16 + l15) * VPP];
    #pragma unroll
    for (int ks = 0; ks < 7; ++ks) {
        bf16x8 ap2 = *(const bf16x8*)&prow[ks * 32 + quad * 8];
        bf16x8 bv0 = *(const bf16x8*)&Vlds[l15 * VPP + ks * 32 + quad * 8];
        bf16x8 bv1 = *(const bf16x8*)&Vlds[(16 + l15) * VPP + ks * 32 + quad * 8];
        acc0 = __builtin_amdgcn_mfma_f32_16x16x32_bf16(ap2, bv0, acc0, 0, 0, 0);
        acc1 = __builtin_amdgcn_mfma_f32_16x16x32_bf16(ap2, bv1, acc1, 0, 0, 0);
    }

    // ---- write back into q plane (in-place, disjoint pixels per block/wave)
    ushort_t* op = qkv + (((size_t)b * HEADS + h) * HW) * DD;
    #pragma unroll
    for (int e = 0; e < 4; ++e) {
        int q2 = wv * 16 + quad * 4 + e;       // output row = query quad*4+e
        int pix = (i0 + (q2 >> 3)) * HH + j0 + (q2 & 7);
        op[(size_t)pix * DD + l15] = f2bf(acc0[e]);
        op[(size_t)pix * DD + 16 + l15] = f2bf(acc1[e]);
    }
}

// ---------------- GEMM3: y = attn_out (bf16, q plane) . proj_w^T (f32) + b; OUT f32 -----
__global__ __launch_bounds__(256) void proj_gemm_kernel(const ushort_t* __restrict__ ao,
                                                        const float* __restrict__ w,
                                                        const float* __restrict__ bias,
                                                        float* __restrict__ out) {
    __shared__ __align__(16) ushort_t lds_p[64 * LP];
    __shared__ __align__(16) ushort_t lds_q[128 * LP];
    const int K = CC;
    int tid = threadIdx.x;
    int b = blockIdx.z;
    int p0 = blockIdx.x * 64;
    int c0 = blockIdx.y * 128;
    int lane = tid & 63, wv = tid >> 6;
    int wp = wv & 1, wq = wv >> 1;
    int quad = lane >> 4, l15 = lane & 15;

    f32x4 acc[2][4];
    #pragma unroll
    for (int i = 0; i < 2; ++i)
        #pragma unroll
        for (int jq = 0; jq < 4; ++jq) acc[i][jq] = (f32x4){0.f, 0.f, 0.f, 0.f};

    const ushort_t* abase = ao + ((size_t)b * HEADS) * HW * DD;

    for (int kt = 0; kt < K / 32; ++kt) {
        __syncthreads();
        {
            int row = tid >> 2, k8 = (tid & 3) * 8;
            uint4_t u = *(const uint4_t*)(abase + ((size_t)kt * HW + p0 + row) * DD + k8);
            *(uint4_t*)&lds_p[row * LP + k8] = u;
        }
        #pragma unroll
        for (int r = 0; r < 2; ++r) {
            int chunk = tid + r * 256;
            int row = chunk >> 2, k8 = (chunk & 3) * 8;
            const float* src = w + (size_t)(c0 + row) * K + kt * 32 + k8;
            float4 f0 = *(const float4*)src;
            float4 f1 = *(const float4*)(src + 4);
            uint4_t u;
            u[0] = pack2(f0.x, f0.y);
            u[1] = pack2(f0.z, f0.w);
            u[2] = pack2(f1.x, f1.y);
            u[3] = pack2(f1.z, f1.w);
            *(uint4_t*)&lds_q[row * LP + k8] = u;
        }
        __syncthreads();
        bf16x8 afrag[2], bfrag[4];
        #pragma unroll
        for (int i = 0; i < 2; ++i)
            afrag[i] = *(const bf16x8*)&lds_p[(wp * 32 + i * 16 + l15) * LP + quad * 8];
        #pragma unroll
        for (int jq = 0; jq < 4; ++jq)
            bfrag[jq] = *(const bf16x8*)&lds_q[(wq * 64 + jq * 16 + l15) * LP + quad * 8];
        #pragma unroll
        for (int i = 0; i < 2; ++i)
            #pragma unroll
            for (int jq = 0; jq < 4; ++jq)
                acc[i][jq] = __builtin_amdgcn_mfma_f32_16x16x32_bf16(afrag[i], bfrag[jq],
                                                                     acc[i][jq], 0, 0, 0);
    }
    #pragma unroll
    for (int i = 0; i < 2; ++i) {
        int pix = p0 + wp * 32 + i * 16 + quad * 4;
        #pragma unroll
        for (int jq = 0; jq < 4; ++jq) {
            int cch = c0 + wq * 64 + jq * 16 + l15;
            float bz = bias[cch];
            float4 v;
            v.x = acc[i][jq][0] + bz;
            v.y = acc[i][jq][1] + bz;
            v.z = acc[i][jq][2] + bz;
            v.w = acc[i][jq][3] + bz;
            float* dst = out + ((size_t)b * CC + cch) * HW + pix;
            *(float4*)dst = v;
        }
    }
}

extern "C" void kernel_launch(void* const* d_in, const int* in_sizes, int n_in,
                              void* d_out, int out_size, void* d_ws, size_t ws_size,
                              hipStream_t stream) {
    const float* x = (const float*)d_in[0];
    const float* qkv_w = (const float*)d_in[1];
    const float* rpb = (const float*)d_in[2];
    const float* proj_w = (const float*)d_in[3];
    const float* proj_b = (const float*)d_in[4];
    float* out = (float*)d_out;

    size_t need = 3 * PLANE * sizeof(ushort_t);   // 73.5 MB
    if (ws_size < need) {
        zero_out_f32<<<dim3((int)((OUT_TOT + 255) / 256)), dim3(256), 0, stream>>>(out);
        return;
    }

    ushort_t* qkv = (ushort_t*)d_ws;         // q/k/v: 3 bf16 planes

    qkv_gemm_kernel<<<dim3(49, 12, 8), dim3(256), 0, stream>>>(x, qkv_w, qkv);
    attn_mfma<<<dim3(49, HEADS, BATCH), dim3(256), 0, stream>>>(qkv, rpb);
    proj_gemm_kernel<<<dim3(49, 4, 8), dim3(256), 0, stream>>>(qkv, proj_w, proj_b, out);
}

// Round 3
// 304.835 us; speedup vs baseline: 1.6584x; 1.0852x over previous
//
#include <hip/hip_runtime.h>

// NeighborhoodAttention2D: B=8, C=512, H=W=56, heads=16, d=32, KSZ=7
// Round 11: attack GEMM1 (128us, VALUBusy 63% / MfmaUtil 13%, FETCH 375MB).
//  - prep pass: convert x, qkv_w, proj_w to bf16 ONCE (ws +26.3MB -> 100MB total)
//  - qkv_gemm_bf16: 256n x 64px tile (x re-reads 12->6), pure-copy staging
//  - proj_gemm_bf16: staging is pure uint4 copies
//  - attn_mfma unchanged (green, round 10)
//  - fallback: if ws < 100MB, run the round-10 f32-staging path (correct, slower)

typedef unsigned short ushort_t;
typedef short bf16x8 __attribute__((ext_vector_type(8)));      // 8 bf16 = 4 VGPRs (MFMA A/B frag)
typedef float f32x4 __attribute__((ext_vector_type(4)));       // MFMA C/D frag
typedef unsigned int uint4_t __attribute__((ext_vector_type(4)));
typedef unsigned int uint2_t __attribute__((ext_vector_type(2)));

#define BATCH 8
#define HEADS 16
#define HW 3136
#define HH 56
#define DD 32
#define CC 512
#define PLANE ((size_t)BATCH * HEADS * HW * DD)   // 12,845,056 elems (= B*C*HW)
#define OUT_TOT ((size_t)BATCH * CC * HW)
#define LP 40                                      // GEMM LDS row pitch (elems); 80B rows

// attention tile geometry
#define KT 14
#define KEYS 224
#define KP 40
#define VPP 232

#define WQ_ELEMS (1536 * 512)
#define WP_ELEMS (512 * 512)

__device__ __forceinline__ float bflo(unsigned int u) {
    union { unsigned int i; float f; } v; v.i = u << 16; return v.f;
}
__device__ __forceinline__ float bfhi(unsigned int u) {
    union { unsigned int i; float f; } v; v.i = u & 0xFFFF0000u; return v.f;
}
__device__ __forceinline__ ushort_t f2bf(float f) {
    union { float f; unsigned int i; } v; v.f = f;
    unsigned int r = v.i + 0x7FFFu + ((v.i >> 16) & 1u);   // RNE
    return (ushort_t)(r >> 16);
}
__device__ __forceinline__ unsigned int pack2(float a, float b) {
    return (unsigned int)f2bf(a) | ((unsigned int)f2bf(b) << 16);
}

__global__ __launch_bounds__(256) void zero_out_f32(float* __restrict__ out) {
    size_t idx = (size_t)blockIdx.x * 256 + threadIdx.x;
    if (idx < OUT_TOT) out[idx] = 0.f;
}

// ---------------- prep: f32 -> bf16, 8 elems/thread ----------------
__global__ __launch_bounds__(256) void cvt_f32_bf16(const float* __restrict__ src,
                                                    ushort_t* __restrict__ dst, int n8) {
    int idx = blockIdx.x * 256 + threadIdx.x;
    if (idx >= n8) return;
    const float4* s = (const float4*)src + (size_t)idx * 2;
    float4 f0 = s[0], f1 = s[1];
    uint4_t u;
    u[0] = pack2(f0.x, f0.y);
    u[1] = pack2(f0.z, f0.w);
    u[2] = pack2(f1.x, f1.y);
    u[3] = pack2(f1.z, f1.w);
    *(uint4_t*)(dst + (size_t)idx * 8) = u;
}

// ---------------- GEMM1 (bf16 path): qkv^T = wq (1536x512 bf16) . xb ([b][c][hw] bf16) ----
// tile 256 (n) x 64 (pixel), BK=32, 4 waves (2x2), 8x2 subtiles/wave.
__global__ __launch_bounds__(256) void qkv_gemm_bf16(const ushort_t* __restrict__ xb,
                                                     const ushort_t* __restrict__ w,
                                                     ushort_t* __restrict__ qkv) {
    __shared__ __align__(16) ushort_t lds_p[256 * LP];   // 20480 B
    __shared__ __align__(16) ushort_t lds_q[64 * LP];    //  5120 B
    int tid = threadIdx.x;
    int b = blockIdx.z;
    int n0 = blockIdx.y * 256;
    int p0 = blockIdx.x * 64;
    int lane = tid & 63, wv = tid >> 6;
    int wp = wv & 1, wq = wv >> 1;
    int quad = lane >> 4, l15 = lane & 15;

    f32x4 acc[8][2];
    #pragma unroll
    for (int i = 0; i < 8; ++i)
        #pragma unroll
        for (int jq = 0; jq < 2; ++jq) acc[i][jq] = (f32x4){0.f, 0.f, 0.f, 0.f};

    int spx = tid & 63;
    int sk8 = (tid >> 6) * 8;

    for (int kt = 0; kt < CC / 32; ++kt) {
        __syncthreads();
        #pragma unroll
        for (int r = 0; r < 4; ++r) {      // A: 256 rows x 32 k, pure uint4 copy
            int chunk = tid + r * 256;
            int row = chunk >> 2, k8 = (chunk & 3) * 8;
            *(uint4_t*)&lds_p[row * LP + k8] =
                *(const uint4_t*)(w + (size_t)(n0 + row) * CC + kt * 32 + k8);
        }
        {                                   // B: x bf16 [k][pixel] -> LDS [pixel][k]
            const ushort_t* xcol = xb + ((size_t)b * CC + kt * 32 + sk8) * HW + p0 + spx;
            unsigned v0 = xcol[0];
            unsigned v1 = xcol[(size_t)HW];
            unsigned v2 = xcol[(size_t)2 * HW];
            unsigned v3 = xcol[(size_t)3 * HW];
            unsigned v4 = xcol[(size_t)4 * HW];
            unsigned v5 = xcol[(size_t)5 * HW];
            unsigned v6 = xcol[(size_t)6 * HW];
            unsigned v7 = xcol[(size_t)7 * HW];
            uint4_t u;
            u[0] = v0 | (v1 << 16);
            u[1] = v2 | (v3 << 16);
            u[2] = v4 | (v5 << 16);
            u[3] = v6 | (v7 << 16);
            *(uint4_t*)&lds_q[spx * LP + sk8] = u;
        }
        __syncthreads();
        bf16x8 afrag[8], bfrag[2];
        #pragma unroll
        for (int i = 0; i < 8; ++i)
            afrag[i] = *(const bf16x8*)&lds_p[(wp * 128 + i * 16 + l15) * LP + quad * 8];
        #pragma unroll
        for (int jq = 0; jq < 2; ++jq)
            bfrag[jq] = *(const bf16x8*)&lds_q[(wq * 32 + jq * 16 + l15) * LP + quad * 8];
        #pragma unroll
        for (int i = 0; i < 8; ++i)
            #pragma unroll
            for (int jq = 0; jq < 2; ++jq)
                acc[i][jq] = __builtin_amdgcn_mfma_f32_16x16x32_bf16(afrag[i], bfrag[jq],
                                                                     acc[i][jq], 0, 0, 0);
    }
    const float qscale = 0.17677669529663687f;   // 1/sqrt(32)
    #pragma unroll
    for (int i = 0; i < 8; ++i) {
        int nbase = n0 + wp * 128 + i * 16 + quad * 4;
        int which = nbase >> 9;
        int h = (nbase >> 5) & 15;
        int dch = nbase & 31;
        float sc = (which == 0) ? qscale : 1.0f;
        #pragma unroll
        for (int jq = 0; jq < 2; ++jq) {
            int pix = p0 + wq * 32 + jq * 16 + l15;
            uint2_t v;
            v[0] = pack2(acc[i][jq][0] * sc, acc[i][jq][1] * sc);
            v[1] = pack2(acc[i][jq][2] * sc, acc[i][jq][3] * sc);
            ushort_t* dst = qkv + (size_t)which * PLANE +
                            ((((size_t)b * HEADS + h) * HW + pix) * DD + dch);
            *(uint2_t*)dst = v;
        }
    }
}

// ---------------- GEMM1 fallback (f32 inputs, round-10 version) ----------------
__global__ __launch_bounds__(256) void qkv_gemm_kernel(const float* __restrict__ x,
                                                       const float* __restrict__ w,
                                                       ushort_t* __restrict__ qkv) {
    __shared__ __align__(16) ushort_t lds_p[128 * LP];
    __shared__ __align__(16) ushort_t lds_q[64 * LP];
    const int K = CC;
    int tid = threadIdx.x;
    int b = blockIdx.z;
    int n0 = blockIdx.y * 128;
    int p0 = blockIdx.x * 64;
    int lane = tid & 63, wv = tid >> 6;
    int wp = wv & 1, wq = wv >> 1;
    int quad = lane >> 4, l15 = lane & 15;

    f32x4 acc[4][2];
    #pragma unroll
    for (int i = 0; i < 4; ++i)
        #pragma unroll
        for (int jq = 0; jq < 2; ++jq) acc[i][jq] = (f32x4){0.f, 0.f, 0.f, 0.f};

    int spx = tid & 63;
    int sk8 = (tid >> 6) * 8;

    for (int kt = 0; kt < K / 32; ++kt) {
        __syncthreads();
        #pragma unroll
        for (int r = 0; r < 2; ++r) {
            int chunk = tid + r * 256;
            int row = chunk >> 2, k8 = (chunk & 3) * 8;
            const float* src = w + (size_t)(n0 + row) * K + kt * 32 + k8;
            float4 f0 = *(const float4*)src;
            float4 f1 = *(const float4*)(src + 4);
            uint4_t u;
            u[0] = pack2(f0.x, f0.y);
            u[1] = pack2(f0.z, f0.w);
            u[2] = pack2(f1.x, f1.y);
            u[3] = pack2(f1.z, f1.w);
            *(uint4_t*)&lds_p[row * LP + k8] = u;
        }
        {
            const float* xcol = x + ((size_t)b * CC + kt * 32 + sk8) * HW + p0 + spx;
            float v0 = xcol[0];
            float v1 = xcol[(size_t)HW];
            float v2 = xcol[(size_t)2 * HW];
            float v3 = xcol[(size_t)3 * HW];
            float v4 = xcol[(size_t)4 * HW];
            float v5 = xcol[(size_t)5 * HW];
            float v6 = xcol[(size_t)6 * HW];
            float v7 = xcol[(size_t)7 * HW];
            uint4_t u;
            u[0] = pack2(v0, v1);
            u[1] = pack2(v2, v3);
            u[2] = pack2(v4, v5);
            u[3] = pack2(v6, v7);
            *(uint4_t*)&lds_q[spx * LP + sk8] = u;
        }
        __syncthreads();
        bf16x8 afrag[4], bfrag[2];
        #pragma unroll
        for (int i = 0; i < 4; ++i)
            afrag[i] = *(const bf16x8*)&lds_p[(wp * 64 + i * 16 + l15) * LP + quad * 8];
        #pragma unroll
        for (int jq = 0; jq < 2; ++jq)
            bfrag[jq] = *(const bf16x8*)&lds_q[(wq * 32 + jq * 16 + l15) * LP + quad * 8];
        #pragma unroll
        for (int i = 0; i < 4; ++i)
            #pragma unroll
            for (int jq = 0; jq < 2; ++jq)
                acc[i][jq] = __builtin_amdgcn_mfma_f32_16x16x32_bf16(afrag[i], bfrag[jq],
                                                                     acc[i][jq], 0, 0, 0);
    }
    const float qscale = 0.17677669529663687f;
    #pragma unroll
    for (int i = 0; i < 4; ++i) {
        int nbase = n0 + wp * 64 + i * 16 + quad * 4;
        int which = nbase >> 9;
        int h = (nbase >> 5) & 15;
        int dch = nbase & 31;
        float sc = (which == 0) ? qscale : 1.0f;
        #pragma unroll
        for (int jq = 0; jq < 2; ++jq) {
            int pix = p0 + wq * 32 + jq * 16 + l15;
            uint2_t v;
            v[0] = pack2(acc[i][jq][0] * sc, acc[i][jq][1] * sc);
            v[1] = pack2(acc[i][jq][2] * sc, acc[i][jq][3] * sc);
            ushort_t* dst = qkv + (size_t)which * PLANE +
                            ((((size_t)b * HEADS + h) * HW + pix) * DD + dch);
            *(uint2_t*)dst = v;
        }
    }
}

// ---------------- MFMA attention: one block per (b, h, 8x8 query tile) ----------------
__global__ __launch_bounds__(256) void attn_mfma(ushort_t* __restrict__ qkv,
                                                 const float* __restrict__ rpb) {
    __shared__ __align__(16) ushort_t Klds[KEYS * KP];       // 17920 B
    __shared__ __align__(16) ushort_t Vlds[DD * VPP];        // 14848 B
    __shared__ __align__(16) ushort_t Plds[64 * VPP];        // 29696 B
    __shared__ float rpbl[169];

    int tid = threadIdx.x;
    int b = blockIdx.z, h = blockIdx.y;
    int tile = blockIdx.x;
    int ti = tile / 7, tj = tile - ti * 7;
    int i0 = ti * 8, j0 = tj * 8;
    int kr0 = min(max(i0 - 3, 0), HH - 14);
    int kc0 = min(max(j0 - 3, 0), HH - 14);

    const ushort_t* qp = qkv + (((size_t)b * HEADS + h) * HW) * DD;
    const ushort_t* kp = qp + PLANE;
    const ushort_t* vp = qp + 2 * PLANE;

    if (tid < 169) rpbl[tid] = rpb[h * 169 + tid];

    #pragma unroll
    for (int r = 0; r < 4; ++r) {
        int idx = tid + r * 256;
        if (idx < 784) {
            int u = idx / 56;
            int rem = idx - u * 56;
            int w = rem >> 2, d8 = (rem & 3) << 3;
            const ushort_t* src = kp + ((size_t)((kr0 + u) * HH + kc0 + w)) * DD + d8;
            *(uint4_t*)&Klds[(u * 16 + w) * KP + d8] = *(const uint4_t*)src;
        } else if (idx < 896) {
            int z = idx - 784;
            int u = z >> 3, rem = z & 7;
            int w = 14 + (rem >> 2), d8 = (rem & 3) << 3;
            *(uint4_t*)&Klds[(u * 16 + w) * KP + d8] = (uint4_t){0, 0, 0, 0};
        }
    }
    #pragma unroll
    for (int rr = 0; rr < 2; ++rr) {
        int idx = tid + rr * 256;
        if (idx < 448) {
            int u = idx >> 5, rem = idx & 31;
            int pr = rem >> 2, d8 = (rem & 3) << 3;
            int kk0 = u * 16 + pr * 2;
            if (pr < 7) {
                const ushort_t* s0 = vp + ((size_t)((kr0 + u) * HH + kc0 + pr * 2)) * DD + d8;
                uint4_t a = *(const uint4_t*)s0;
                uint4_t c = *(const uint4_t*)(s0 + DD);
                #pragma unroll
                for (int e = 0; e < 4; ++e) {
                    unsigned lo = (a[e] & 0xFFFFu) | (c[e] << 16);
                    unsigned hi = (a[e] >> 16) | (c[e] & 0xFFFF0000u);
                    *(unsigned*)&Vlds[(d8 + 2 * e) * VPP + kk0] = lo;
                    *(unsigned*)&Vlds[(d8 + 2 * e + 1) * VPP + kk0] = hi;
                }
            } else {
                #pragma unroll
                for (int e = 0; e < 8; ++e)
                    *(unsigned*)&Vlds[(d8 + e) * VPP + kk0] = 0;
            }
        }
    }

    int lane = tid & 63, wv = tid >> 6;
    int l15 = lane & 15, quad = lane >> 4;
    int q_idx = wv * 16 + l15;
    int qi = i0 + (q_idx >> 3), qj = j0 + (q_idx & 7);
    int si = min(max(qi - 3, 0), HH - 7);
    int sj = min(max(qj - 3, 0), HH - 7);

    bf16x8 bq = *(const bf16x8*)(qp + ((size_t)(qi * HH + qj)) * DD + quad * 8);

    int jbase = kc0 + quad * 4 - sj;
    int cbase = kc0 + quad * 4 - qj + 6;
    int coff[4];
    bool cok[4];
    #pragma unroll
    for (int r2 = 0; r2 < 4; ++r2) {
        cok[r2] = (unsigned)(jbase + r2) <= 6u;
        coff[r2] = min(max(cbase + r2, 0), 12);
    }

    __syncthreads();

    f32x4 lg[KT];
    f32x4 zf = {0.f, 0.f, 0.f, 0.f};
    #pragma unroll
    for (int t = 0; t < KT; ++t) {
        bf16x8 ak = *(const bf16x8*)&Klds[(t * 16 + l15) * KP + quad * 8];
        lg[t] = __builtin_amdgcn_mfma_f32_16x16x32_bf16(ak, bq, zf, 0, 0, 0);
    }

    int abase = kr0 - qi + 6;
    #pragma unroll
    for (int t = 0; t < KT; ++t) {
        bool rok = (unsigned)(kr0 + t - si) <= 6u;
        int arow = min(max(abase + t, 0), 12);
        const float* br = &rpbl[arow * 13];
        #pragma unroll
        for (int r2 = 0; r2 < 4; ++r2) {
            float bias = br[coff[r2]];
            lg[t][r2] = (rok && cok[r2]) ? lg[t][r2] + bias : -1e30f;
        }
    }

    float m = -1e30f;
    #pragma unroll
    for (int t = 0; t < KT; ++t)
        #pragma unroll
        for (int r2 = 0; r2 < 4; ++r2) m = fmaxf(m, lg[t][r2]);
    m = fmaxf(m, __shfl_xor(m, 16));
    m = fmaxf(m, __shfl_xor(m, 32));
    float s = 0.f;
    #pragma unroll
    for (int t = 0; t < KT; ++t)
        #pragma unroll
        for (int r2 = 0; r2 < 4; ++r2) {
            float e = __expf(lg[t][r2] - m);
            lg[t][r2] = e;
            s += e;
        }
    s += __shfl_xor(s, 16);
    s += __shfl_xor(s, 32);
    float inv = 1.f / s;

    ushort_t* pw = &Plds[(wv * 16 + l15) * VPP];
    #pragma unroll
    for (int t = 0; t < KT; ++t) {
        uint2_t u;
        u[0] = pack2(lg[t][0] * inv, lg[t][1] * inv);
        u[1] = pack2(lg[t][2] * inv, lg[t][3] * inv);
        *(uint2_t*)&pw[t * 16 + quad * 4] = u;
    }

    __syncthreads();

    f32x4 acc0 = zf, acc1 = zf;
    const ushort_t* prow = &Plds[(wv * 16 + l15) * VPP];
    #pragma unroll
    for (int ks = 0; ks < 7; ++ks) {
        bf16x8 ap2 = *(const bf16x8*)&prow[ks * 32 + quad * 8];
        bf16x8 bv0 = *(const bf16x8*)&Vlds[l15 * VPP + ks * 32 + quad * 8];
        bf16x8 bv1 = *(const bf16x8*)&Vlds[(16 + l15) * VPP + ks * 32 + quad * 8];
        acc0 = __builtin_amdgcn_mfma_f32_16x16x32_bf16(ap2, bv0, acc0, 0, 0, 0);
        acc1 = __builtin_amdgcn_mfma_f32_16x16x32_bf16(ap2, bv1, acc1, 0, 0, 0);
    }

    ushort_t* op = qkv + (((size_t)b * HEADS + h) * HW) * DD;
    #pragma unroll
    for (int e = 0; e < 4; ++e) {
        int q2 = wv * 16 + quad * 4 + e;
        int pix = (i0 + (q2 >> 3)) * HH + j0 + (q2 & 7);
        op[(size_t)pix * DD + l15] = f2bf(acc0[e]);
        op[(size_t)pix * DD + 16 + l15] = f2bf(acc1[e]);
    }
}

// ---------------- GEMM3 (bf16 path): y = attn_out . wpb^T + b; OUT f32 ----------------
__global__ __launch_bounds__(256) void proj_gemm_bf16(const ushort_t* __restrict__ ao,
                                                      const ushort_t* __restrict__ w,
                                                      const float* __restrict__ bias,
                                                      float* __restrict__ out) {
    __shared__ __align__(16) ushort_t lds_p[64 * LP];
    __shared__ __align__(16) ushort_t lds_q[128 * LP];
    int tid = threadIdx.x;
    int b = blockIdx.z;
    int p0 = blockIdx.x * 64;
    int c0 = blockIdx.y * 128;
    int lane = tid & 63, wv = tid >> 6;
    int wp = wv & 1, wq = wv >> 1;
    int quad = lane >> 4, l15 = lane & 15;

    f32x4 acc[2][4];
    #pragma unroll
    for (int i = 0; i < 2; ++i)
        #pragma unroll
        for (int jq = 0; jq < 4; ++jq) acc[i][jq] = (f32x4){0.f, 0.f, 0.f, 0.f};

    const ushort_t* abase = ao + ((size_t)b * HEADS) * HW * DD;

    for (int kt = 0; kt < CC / 32; ++kt) {
        __syncthreads();
        {
            int row = tid >> 2, k8 = (tid & 3) * 8;
            uint4_t u = *(const uint4_t*)(abase + ((size_t)kt * HW + p0 + row) * DD + k8);
            *(uint4_t*)&lds_p[row * LP + k8] = u;
        }
        #pragma unroll
        for (int r = 0; r < 2; ++r) {
            int chunk = tid + r * 256;
            int row = chunk >> 2, k8 = (chunk & 3) * 8;
            *(uint4_t*)&lds_q[row * LP + k8] =
                *(const uint4_t*)(w + (size_t)(c0 + row) * CC + kt * 32 + k8);
        }
        __syncthreads();
        bf16x8 afrag[2], bfrag[4];
        #pragma unroll
        for (int i = 0; i < 2; ++i)
            afrag[i] = *(const bf16x8*)&lds_p[(wp * 32 + i * 16 + l15) * LP + quad * 8];
        #pragma unroll
        for (int jq = 0; jq < 4; ++jq)
            bfrag[jq] = *(const bf16x8*)&lds_q[(wq * 64 + jq * 16 + l15) * LP + quad * 8];
        #pragma unroll
        for (int i = 0; i < 2; ++i)
            #pragma unroll
            for (int jq = 0; jq < 4; ++jq)
                acc[i][jq] = __builtin_amdgcn_mfma_f32_16x16x32_bf16(afrag[i], bfrag[jq],
                                                                     acc[i][jq], 0, 0, 0);
    }
    #pragma unroll
    for (int i = 0; i < 2; ++i) {
        int pix = p0 + wp * 32 + i * 16 + quad * 4;
        #pragma unroll
        for (int jq = 0; jq < 4; ++jq) {
            int cch = c0 + wq * 64 + jq * 16 + l15;
            float bz = bias[cch];
            float4 v;
            v.x = acc[i][jq][0] + bz;
            v.y = acc[i][jq][1] + bz;
            v.z = acc[i][jq][2] + bz;
            v.w = acc[i][jq][3] + bz;
            float* dst = out + ((size_t)b * CC + cch) * HW + pix;
            *(float4*)dst = v;
        }
    }
}

// ---------------- GEMM3 fallback (f32 w, round-10 version) ----------------
__global__ __launch_bounds__(256) void proj_gemm_kernel(const ushort_t* __restrict__ ao,
                                                        const float* __restrict__ w,
                                                        const float* __restrict__ bias,
                                                        float* __restrict__ out) {
    __shared__ __align__(16) ushort_t lds_p[64 * LP];
    __shared__ __align__(16) ushort_t lds_q[128 * LP];
    const int K = CC;
    int tid = threadIdx.x;
    int b = blockIdx.z;
    int p0 = blockIdx.x * 64;
    int c0 = blockIdx.y * 128;
    int lane = tid & 63, wv = tid >> 6;
    int wp = wv & 1, wq = wv >> 1;
    int quad = lane >> 4, l15 = lane & 15;

    f32x4 acc[2][4];
    #pragma unroll
    for (int i = 0; i < 2; ++i)
        #pragma unroll
        for (int jq = 0; jq < 4; ++jq) acc[i][jq] = (f32x4){0.f, 0.f, 0.f, 0.f};

    const ushort_t* abase = ao + ((size_t)b * HEADS) * HW * DD;

    for (int kt = 0; kt < K / 32; ++kt) {
        __syncthreads();
        {
            int row = tid >> 2, k8 = (tid & 3) * 8;
            uint4_t u = *(const uint4_t*)(abase + ((size_t)kt * HW + p0 + row) * DD + k8);
            *(uint4_t*)&lds_p[row * LP + k8] = u;
        }
        #pragma unroll
        for (int r = 0; r < 2; ++r) {
            int chunk = tid + r * 256;
            int row = chunk >> 2, k8 = (chunk & 3) * 8;
            const float* src = w + (size_t)(c0 + row) * K + kt * 32 + k8;
            float4 f0 = *(const float4*)src;
            float4 f1 = *(const float4*)(src + 4);
            uint4_t u;
            u[0] = pack2(f0.x, f0.y);
            u[1] = pack2(f0.z, f0.w);
            u[2] = pack2(f1.x, f1.y);
            u[3] = pack2(f1.z, f1.w);
            *(uint4_t*)&lds_q[row * LP + k8] = u;
        }
        __syncthreads();
        bf16x8 afrag[2], bfrag[4];
        #pragma unroll
        for (int i = 0; i < 2; ++i)
            afrag[i] = *(const bf16x8*)&lds_p[(wp * 32 + i * 16 + l15) * LP + quad * 8];
        #pragma unroll
        for (int jq = 0; jq < 4; ++jq)
            bfrag[jq] = *(const bf16x8*)&lds_q[(wq * 64 + jq * 16 + l15) * LP + quad * 8];
        #pragma unroll
        for (int i = 0; i < 2; ++i)
            #pragma unroll
            for (int jq = 0; jq < 4; ++jq)
                acc[i][jq] = __builtin_amdgcn_mfma_f32_16x16x32_bf16(afrag[i], bfrag[jq],
                                                                     acc[i][jq], 0, 0, 0);
    }
    #pragma unroll
    for (int i = 0; i < 2; ++i) {
        int pix = p0 + wp * 32 + i * 16 + quad * 4;
        #pragma unroll
        for (int jq = 0; jq < 4; ++jq) {
            int cch = c0 + wq * 64 + jq * 16 + l15;
            float bz = bias[cch];
            float4 v;
            v.x = acc[i][jq][0] + bz;
            v.y = acc[i][jq][1] + bz;
            v.z = acc[i][jq][2] + bz;
            v.w = acc[i][jq][3] + bz;
            float* dst = out + ((size_t)b * CC + cch) * HW + pix;
            *(float4*)dst = v;
        }
    }
}

extern "C" void kernel_launch(void* const* d_in, const int* in_sizes, int n_in,
                              void* d_out, int out_size, void* d_ws, size_t ws_size,
                              hipStream_t stream) {
    const float* x = (const float*)d_in[0];
    const float* qkv_w = (const float*)d_in[1];
    const float* rpb = (const float*)d_in[2];
    const float* proj_w = (const float*)d_in[3];
    const float* proj_b = (const float*)d_in[4];
    float* out = (float*)d_out;

    size_t need_min = 3 * PLANE * sizeof(ushort_t);                       // 73.5 MB
    size_t need_full = (4 * PLANE + WQ_ELEMS + WP_ELEMS) * sizeof(ushort_t);  // 100 MB

    if (ws_size < need_min) {
        zero_out_f32<<<dim3((int)((OUT_TOT + 255) / 256)), dim3(256), 0, stream>>>(out);
        return;
    }

    ushort_t* qkv = (ushort_t*)d_ws;                 // q/k/v: 3 bf16 planes

    if (ws_size >= need_full) {
        ushort_t* xbf = qkv + 3 * PLANE;             // bf16 x, [b][c][hw]
        ushort_t* wqb = qkv + 4 * PLANE;             // bf16 qkv_w
        ushort_t* wpb = wqb + WQ_ELEMS;              // bf16 proj_w

        int n8x = (int)(PLANE / 8);                  // 1,605,632
        cvt_f32_bf16<<<dim3((n8x + 255) / 256), dim3(256), 0, stream>>>(x, xbf, n8x);
        cvt_f32_bf16<<<dim3((WQ_ELEMS / 8 + 255) / 256), dim3(256), 0, stream>>>(
            qkv_w, wqb, WQ_ELEMS / 8);
        cvt_f32_bf16<<<dim3((WP_ELEMS / 8 + 255) / 256), dim3(256), 0, stream>>>(
            proj_w, wpb, WP_ELEMS / 8);

        qkv_gemm_bf16<<<dim3(49, 6, 8), dim3(256), 0, stream>>>(xbf, wqb, qkv);
        attn_mfma<<<dim3(49, HEADS, BATCH), dim3(256), 0, stream>>>(qkv, rpb);
        proj_gemm_bf16<<<dim3(49, 4, 8), dim3(256), 0, stream>>>(qkv, wpb, proj_b, out);
    } else {
        qkv_gemm_kernel<<<dim3(49, 12, 8), dim3(256), 0, stream>>>(x, qkv_w, qkv);
        attn_mfma<<<dim3(49, HEADS, BATCH), dim3(256), 0, stream>>>(qkv, rpb);
        proj_gemm_kernel<<<dim3(49, 4, 8), dim3(256), 0, stream>>>(qkv, proj_w, proj_b, out);
    }
}

// Round 4
// 272.424 us; speedup vs baseline: 1.8557x; 1.1190x over previous
//
#include <hip/hip_runtime.h>

// NeighborhoodAttention2D: B=8, C=512, H=W=56, heads=16, d=32, KSZ=7
// Round 12: attn occupancy + conflict fix (103us, Occ 21%, LDS 63.5KB, 9.8M conflicts).
//  - PV now uses v_mfma_f32_16x16x16_bf16 per 16-key tile: its A-operand layout
//    (row=l15, k=quad*4+e) EQUALS the swapped-QK D layout (col=l15, row=quad*4+r)
//    -> P stays in registers. Plds (29.7KB) + 2nd barrier + redistribution DELETED.
//  - Klds pitch 40->32 (bank-optimal: start slot (4*(l15&1)+quad) mod 8 uniform).
//  - Vlds pitch 232->228 (d8*114 mod 32 = {0,16} -> 2-way staging writes, free).
//  - softmax normalization deferred to epilogue (4 shfl + 8 mul vs 56 mul).
//  - LDS 63.5KB -> 28.9KB => 4-5 blocks/CU (was 2).
// GEMM1(bf16)/GEMM3(bf16)/cvt unchanged from green round-11.

typedef unsigned short ushort_t;
typedef short bf16x8 __attribute__((ext_vector_type(8)));      // 8 bf16 = 4 VGPRs
typedef short bf16x4 __attribute__((ext_vector_type(4)));      // 4 bf16 = 2 VGPRs
typedef float f32x4 __attribute__((ext_vector_type(4)));       // MFMA C/D frag
typedef unsigned int uint4_t __attribute__((ext_vector_type(4)));
typedef unsigned int uint2_t __attribute__((ext_vector_type(2)));

#define BATCH 8
#define HEADS 16
#define HW 3136
#define HH 56
#define DD 32
#define CC 512
#define PLANE ((size_t)BATCH * HEADS * HW * DD)   // 12,845,056 elems (= B*C*HW)
#define OUT_TOT ((size_t)BATCH * CC * HW)
#define LP 40                                      // GEMM LDS row pitch (elems); 80B rows

// attention tile geometry
#define KT 14                                      // key tiles (= patch rows)
#define KP 32                                      // Klds pitch: 64B rows, bank-optimal
#define VPP 228                                    // Vlds pitch: 456B rows, 2-way writes

#define WQ_ELEMS (1536 * 512)
#define WP_ELEMS (512 * 512)

__device__ __forceinline__ ushort_t f2bf(float f) {
    union { float f; unsigned int i; } v; v.f = f;
    unsigned int r = v.i + 0x7FFFu + ((v.i >> 16) & 1u);   // RNE
    return (ushort_t)(r >> 16);
}
__device__ __forceinline__ unsigned int pack2(float a, float b) {
    return (unsigned int)f2bf(a) | ((unsigned int)f2bf(b) << 16);
}

__device__ __forceinline__ f32x4 mfma16x16x16(bf16x4 a, bf16x4 b, f32x4 c) {
#if __has_builtin(__builtin_amdgcn_mfma_f32_16x16x16bf16_1k)
    return __builtin_amdgcn_mfma_f32_16x16x16bf16_1k(a, b, c, 0, 0, 0);
#else
    f32x4 d;
    asm("v_mfma_f32_16x16x16_bf16 %0, %1, %2, %3" : "=v"(d) : "v"(a), "v"(b), "v"(c));
    return d;
#endif
}

__global__ __launch_bounds__(256) void zero_out_f32(float* __restrict__ out) {
    size_t idx = (size_t)blockIdx.x * 256 + threadIdx.x;
    if (idx < OUT_TOT) out[idx] = 0.f;
}

// ---------------- prep: f32 -> bf16, 8 elems/thread ----------------
__global__ __launch_bounds__(256) void cvt_f32_bf16(const float* __restrict__ src,
                                                    ushort_t* __restrict__ dst, int n8) {
    int idx = blockIdx.x * 256 + threadIdx.x;
    if (idx >= n8) return;
    const float4* s = (const float4*)src + (size_t)idx * 2;
    float4 f0 = s[0], f1 = s[1];
    uint4_t u;
    u[0] = pack2(f0.x, f0.y);
    u[1] = pack2(f0.z, f0.w);
    u[2] = pack2(f1.x, f1.y);
    u[3] = pack2(f1.z, f1.w);
    *(uint4_t*)(dst + (size_t)idx * 8) = u;
}

// ---------------- GEMM1 (bf16): qkv^T = wq (1536x512) . xb ([b][c][hw]) ----------
__global__ __launch_bounds__(256) void qkv_gemm_bf16(const ushort_t* __restrict__ xb,
                                                     const ushort_t* __restrict__ w,
                                                     ushort_t* __restrict__ qkv) {
    __shared__ __align__(16) ushort_t lds_p[256 * LP];   // 20480 B
    __shared__ __align__(16) ushort_t lds_q[64 * LP];    //  5120 B
    int tid = threadIdx.x;
    int b = blockIdx.z;
    int n0 = blockIdx.y * 256;
    int p0 = blockIdx.x * 64;
    int lane = tid & 63, wv = tid >> 6;
    int wp = wv & 1, wq = wv >> 1;
    int quad = lane >> 4, l15 = lane & 15;

    f32x4 acc[8][2];
    #pragma unroll
    for (int i = 0; i < 8; ++i)
        #pragma unroll
        for (int jq = 0; jq < 2; ++jq) acc[i][jq] = (f32x4){0.f, 0.f, 0.f, 0.f};

    int spx = tid & 63;
    int sk8 = (tid >> 6) * 8;

    for (int kt = 0; kt < CC / 32; ++kt) {
        __syncthreads();
        #pragma unroll
        for (int r = 0; r < 4; ++r) {      // A: 256 rows x 32 k, pure uint4 copy
            int chunk = tid + r * 256;
            int row = chunk >> 2, k8 = (chunk & 3) * 8;
            *(uint4_t*)&lds_p[row * LP + k8] =
                *(const uint4_t*)(w + (size_t)(n0 + row) * CC + kt * 32 + k8);
        }
        {                                   // B: x bf16 [k][pixel] -> LDS [pixel][k]
            const ushort_t* xcol = xb + ((size_t)b * CC + kt * 32 + sk8) * HW + p0 + spx;
            unsigned v0 = xcol[0];
            unsigned v1 = xcol[(size_t)HW];
            unsigned v2 = xcol[(size_t)2 * HW];
            unsigned v3 = xcol[(size_t)3 * HW];
            unsigned v4 = xcol[(size_t)4 * HW];
            unsigned v5 = xcol[(size_t)5 * HW];
            unsigned v6 = xcol[(size_t)6 * HW];
            unsigned v7 = xcol[(size_t)7 * HW];
            uint4_t u;
            u[0] = v0 | (v1 << 16);
            u[1] = v2 | (v3 << 16);
            u[2] = v4 | (v5 << 16);
            u[3] = v6 | (v7 << 16);
            *(uint4_t*)&lds_q[spx * LP + sk8] = u;
        }
        __syncthreads();
        bf16x8 afrag[8], bfrag[2];
        #pragma unroll
        for (int i = 0; i < 8; ++i)
            afrag[i] = *(const bf16x8*)&lds_p[(wp * 128 + i * 16 + l15) * LP + quad * 8];
        #pragma unroll
        for (int jq = 0; jq < 2; ++jq)
            bfrag[jq] = *(const bf16x8*)&lds_q[(wq * 32 + jq * 16 + l15) * LP + quad * 8];
        #pragma unroll
        for (int i = 0; i < 8; ++i)
            #pragma unroll
            for (int jq = 0; jq < 2; ++jq)
                acc[i][jq] = __builtin_amdgcn_mfma_f32_16x16x32_bf16(afrag[i], bfrag[jq],
                                                                     acc[i][jq], 0, 0, 0);
    }
    const float qscale = 0.17677669529663687f;   // 1/sqrt(32)
    #pragma unroll
    for (int i = 0; i < 8; ++i) {
        int nbase = n0 + wp * 128 + i * 16 + quad * 4;
        int which = nbase >> 9;
        int h = (nbase >> 5) & 15;
        int dch = nbase & 31;
        float sc = (which == 0) ? qscale : 1.0f;
        #pragma unroll
        for (int jq = 0; jq < 2; ++jq) {
            int pix = p0 + wq * 32 + jq * 16 + l15;
            uint2_t v;
            v[0] = pack2(acc[i][jq][0] * sc, acc[i][jq][1] * sc);
            v[1] = pack2(acc[i][jq][2] * sc, acc[i][jq][3] * sc);
            ushort_t* dst = qkv + (size_t)which * PLANE +
                            ((((size_t)b * HEADS + h) * HW + pix) * DD + dch);
            *(uint2_t*)dst = v;
        }
    }
}

// ---------------- GEMM1 fallback (f32 inputs) ----------------
__global__ __launch_bounds__(256) void qkv_gemm_kernel(const float* __restrict__ x,
                                                       const float* __restrict__ w,
                                                       ushort_t* __restrict__ qkv) {
    __shared__ __align__(16) ushort_t lds_p[128 * LP];
    __shared__ __align__(16) ushort_t lds_q[64 * LP];
    const int K = CC;
    int tid = threadIdx.x;
    int b = blockIdx.z;
    int n0 = blockIdx.y * 128;
    int p0 = blockIdx.x * 64;
    int lane = tid & 63, wv = tid >> 6;
    int wp = wv & 1, wq = wv >> 1;
    int quad = lane >> 4, l15 = lane & 15;

    f32x4 acc[4][2];
    #pragma unroll
    for (int i = 0; i < 4; ++i)
        #pragma unroll
        for (int jq = 0; jq < 2; ++jq) acc[i][jq] = (f32x4){0.f, 0.f, 0.f, 0.f};

    int spx = tid & 63;
    int sk8 = (tid >> 6) * 8;

    for (int kt = 0; kt < K / 32; ++kt) {
        __syncthreads();
        #pragma unroll
        for (int r = 0; r < 2; ++r) {
            int chunk = tid + r * 256;
            int row = chunk >> 2, k8 = (chunk & 3) * 8;
            const float* src = w + (size_t)(n0 + row) * K + kt * 32 + k8;
            float4 f0 = *(const float4*)src;
            float4 f1 = *(const float4*)(src + 4);
            uint4_t u;
            u[0] = pack2(f0.x, f0.y);
            u[1] = pack2(f0.z, f0.w);
            u[2] = pack2(f1.x, f1.y);
            u[3] = pack2(f1.z, f1.w);
            *(uint4_t*)&lds_p[row * LP + k8] = u;
        }
        {
            const float* xcol = x + ((size_t)b * CC + kt * 32 + sk8) * HW + p0 + spx;
            float v0 = xcol[0];
            float v1 = xcol[(size_t)HW];
            float v2 = xcol[(size_t)2 * HW];
            float v3 = xcol[(size_t)3 * HW];
            float v4 = xcol[(size_t)4 * HW];
            float v5 = xcol[(size_t)5 * HW];
            float v6 = xcol[(size_t)6 * HW];
            float v7 = xcol[(size_t)7 * HW];
            uint4_t u;
            u[0] = pack2(v0, v1);
            u[1] = pack2(v2, v3);
            u[2] = pack2(v4, v5);
            u[3] = pack2(v6, v7);
            *(uint4_t*)&lds_q[spx * LP + sk8] = u;
        }
        __syncthreads();
        bf16x8 afrag[4], bfrag[2];
        #pragma unroll
        for (int i = 0; i < 4; ++i)
            afrag[i] = *(const bf16x8*)&lds_p[(wp * 64 + i * 16 + l15) * LP + quad * 8];
        #pragma unroll
        for (int jq = 0; jq < 2; ++jq)
            bfrag[jq] = *(const bf16x8*)&lds_q[(wq * 32 + jq * 16 + l15) * LP + quad * 8];
        #pragma unroll
        for (int i = 0; i < 4; ++i)
            #pragma unroll
            for (int jq = 0; jq < 2; ++jq)
                acc[i][jq] = __builtin_amdgcn_mfma_f32_16x16x32_bf16(afrag[i], bfrag[jq],
                                                                     acc[i][jq], 0, 0, 0);
    }
    const float qscale = 0.17677669529663687f;
    #pragma unroll
    for (int i = 0; i < 4; ++i) {
        int nbase = n0 + wp * 64 + i * 16 + quad * 4;
        int which = nbase >> 9;
        int h = (nbase >> 5) & 15;
        int dch = nbase & 31;
        float sc = (which == 0) ? qscale : 1.0f;
        #pragma unroll
        for (int jq = 0; jq < 2; ++jq) {
            int pix = p0 + wq * 32 + jq * 16 + l15;
            uint2_t v;
            v[0] = pack2(acc[i][jq][0] * sc, acc[i][jq][1] * sc);
            v[1] = pack2(acc[i][jq][2] * sc, acc[i][jq][3] * sc);
            ushort_t* dst = qkv + (size_t)which * PLANE +
                            ((((size_t)b * HEADS + h) * HW + pix) * DD + dch);
            *(uint2_t*)dst = v;
        }
    }
}

// ---------------- MFMA attention: one block per (b, h, 8x8 query tile) ----------------
__global__ __launch_bounds__(256, 4) void attn_mfma(ushort_t* __restrict__ qkv,
                                                    const float* __restrict__ rpb) {
    __shared__ __align__(16) ushort_t Klds[224 * KP];        // 14336 B, [kk][d]
    __shared__ __align__(16) ushort_t Vlds[DD * VPP];        // 14592 B, [d][kk]
    __shared__ float rpbl[169];                              //   676 B

    int tid = threadIdx.x;
    int b = blockIdx.z, h = blockIdx.y;
    int tile = blockIdx.x;
    int ti = tile / 7, tj = tile - ti * 7;
    int i0 = ti * 8, j0 = tj * 8;
    int kr0 = min(max(i0 - 3, 0), HH - 14);
    int kc0 = min(max(j0 - 3, 0), HH - 14);

    const ushort_t* qp = qkv + (((size_t)b * HEADS + h) * HW) * DD;
    const ushort_t* kp = qp + PLANE;
    const ushort_t* vp = qp + 2 * PLANE;

    if (tid < 169) rpbl[tid] = rpb[h * 169 + tid];

    // ---- stage K patch: Klds[(u*16+w)][d]; zero pad rows w=14,15
    #pragma unroll
    for (int r = 0; r < 4; ++r) {
        int idx = tid + r * 256;
        if (idx < 784) {                       // 14 rows * 14 keys * 4 octets
            int u = idx / 56;
            int rem = idx - u * 56;
            int w = rem >> 2, d8 = (rem & 3) << 3;
            const ushort_t* src = kp + ((size_t)((kr0 + u) * HH + kc0 + w)) * DD + d8;
            *(uint4_t*)&Klds[(u * 16 + w) * KP + d8] = *(const uint4_t*)src;
        } else if (idx < 896) {                // zero 28 pad rows x 4 octets
            int z = idx - 784;
            int u = z >> 3, rem = z & 7;
            int w = 14 + (rem >> 2), d8 = (rem & 3) << 3;
            *(uint4_t*)&Klds[(u * 16 + w) * KP + d8] = (uint4_t){0, 0, 0, 0};
        }
    }
    // ---- stage V transposed: Vlds[d][kk]; zero pad cols kk%16 in {14,15}
    #pragma unroll
    for (int rr = 0; rr < 2; ++rr) {
        int idx = tid + rr * 256;
        if (idx < 448) {                       // 14 rows * 8 key-pairs * 4 octets
            int u = idx >> 5, rem = idx & 31;
            int pr = rem >> 2, d8 = (rem & 3) << 3;
            int kk0 = u * 16 + pr * 2;
            if (pr < 7) {
                const ushort_t* s0 = vp + ((size_t)((kr0 + u) * HH + kc0 + pr * 2)) * DD + d8;
                uint4_t a = *(const uint4_t*)s0;
                uint4_t c = *(const uint4_t*)(s0 + DD);
                #pragma unroll
                for (int e = 0; e < 4; ++e) {
                    unsigned lo = (a[e] & 0xFFFFu) | (c[e] << 16);
                    unsigned hi = (a[e] >> 16) | (c[e] & 0xFFFF0000u);
                    *(unsigned*)&Vlds[(d8 + 2 * e) * VPP + kk0] = lo;
                    *(unsigned*)&Vlds[(d8 + 2 * e + 1) * VPP + kk0] = hi;
                }
            } else {
                #pragma unroll
                for (int e = 0; e < 8; ++e)
                    *(unsigned*)&Vlds[(d8 + e) * VPP + kk0] = 0;
            }
        }
    }

    int lane = tid & 63, wv = tid >> 6;
    int l15 = lane & 15, quad = lane >> 4;
    int q_idx = wv * 16 + l15;                 // this lane's query (B-operand col)
    int qi = i0 + (q_idx >> 3), qj = j0 + (q_idx & 7);
    int si = min(max(qi - 3, 0), HH - 7);
    int sj = min(max(qj - 3, 0), HH - 7);

    // Q fragment straight from global (B operand: lane l15 = query, quad*8 = d octet)
    bf16x8 bq = *(const bf16x8*)(qp + ((size_t)(qi * HH + qj)) * DD + quad * 8);

    // per-lane column tables: key col w = quad*4 + r (constant across patch rows)
    int jbase = kc0 + quad * 4 - sj;           // col valid iff jbase + r in [0,6]
    int cbase = kc0 + quad * 4 - qj + 6;       // rpb col index = cbase + r
    int coff[4];
    bool cok[4];
    #pragma unroll
    for (int r2 = 0; r2 < 4; ++r2) {
        cok[r2] = (unsigned)(jbase + r2) <= 6u;
        coff[r2] = min(max(cbase + r2, 0), 12);
    }

    __syncthreads();

    // ---- QK^T: swapped (A=K, B=Q): lane -> query l15, keys (t*16 + quad*4 + r)
    f32x4 lg[KT];
    f32x4 zf = {0.f, 0.f, 0.f, 0.f};
    #pragma unroll
    for (int t = 0; t < KT; ++t) {
        bf16x8 ak = *(const bf16x8*)&Klds[(t * 16 + l15) * KP + quad * 8];
        lg[t] = __builtin_amdgcn_mfma_f32_16x16x32_bf16(ak, bq, zf, 0, 0, 0);
    }

    // ---- bias + neighborhood mask
    int abase = kr0 - qi + 6;                  // rpb row index = abase + t
    #pragma unroll
    for (int t = 0; t < KT; ++t) {
        bool rok = (unsigned)(kr0 + t - si) <= 6u;
        int arow = min(max(abase + t, 0), 12);
        const float* br = &rpbl[arow * 13];
        #pragma unroll
        for (int r2 = 0; r2 < 4; ++r2) {
            float bias = br[coff[r2]];
            lg[t][r2] = (rok && cok[r2]) ? lg[t][r2] + bias : -1e30f;
        }
    }

    // ---- softmax over 224 keys: in-lane (56) + quad reduce (xor 16, 32); no normalize
    float m = -1e30f;
    #pragma unroll
    for (int t = 0; t < KT; ++t)
        #pragma unroll
        for (int r2 = 0; r2 < 4; ++r2) m = fmaxf(m, lg[t][r2]);
    m = fmaxf(m, __shfl_xor(m, 16));
    m = fmaxf(m, __shfl_xor(m, 32));
    float s = 0.f;
    #pragma unroll
    for (int t = 0; t < KT; ++t)
        #pragma unroll
        for (int r2 = 0; r2 < 4; ++r2) {
            float e = __expf(lg[t][r2] - m);
            lg[t][r2] = e;
            s += e;
        }
    s += __shfl_xor(s, 16);
    s += __shfl_xor(s, 32);
    float inv = 1.f / s;

    // ---- P -> bf16 IN REGISTERS: QK D layout (col=l15 q, row=quad*4+r key)
    //      == 16x16x16 A layout (row=l15 q, k=quad*4+e key). Zero redistribution.
    bf16x4 pb[KT];
    #pragma unroll
    for (int t = 0; t < KT; ++t) {
        union { uint2_t u; bf16x4 v; } cv;
        cv.u[0] = pack2(lg[t][0], lg[t][1]);
        cv.u[1] = pack2(lg[t][2], lg[t][3]);
        pb[t] = cv.v;
    }

    // ---- PV: per 16-key tile, A=P (in-reg), B=V^T tile; 2 d-halves
    f32x4 acc0 = zf, acc1 = zf;
    #pragma unroll
    for (int t = 0; t < KT; ++t) {
        bf16x4 bv0 = *(const bf16x4*)&Vlds[l15 * VPP + t * 16 + quad * 4];
        bf16x4 bv1 = *(const bf16x4*)&Vlds[(16 + l15) * VPP + t * 16 + quad * 4];
        acc0 = mfma16x16x16(pb[t], bv0, acc0);
        acc1 = mfma16x16x16(pb[t], bv1, acc1);
    }

    // ---- normalize in epilogue: D rows = queries quad*4+e; fetch their 1/s by shfl
    ushort_t* op = qkv + (((size_t)b * HEADS + h) * HW) * DD;
    #pragma unroll
    for (int e = 0; e < 4; ++e) {
        float invq = __shfl(inv, quad * 4 + e);     // lane (quad*4+e) holds that query's s
        int q2 = wv * 16 + quad * 4 + e;
        int pix = (i0 + (q2 >> 3)) * HH + j0 + (q2 & 7);
        op[(size_t)pix * DD + l15] = f2bf(acc0[e] * invq);
        op[(size_t)pix * DD + 16 + l15] = f2bf(acc1[e] * invq);
    }
}

// ---------------- GEMM3 (bf16): y = attn_out . wpb^T + b; OUT f32 ----------------
__global__ __launch_bounds__(256) void proj_gemm_bf16(const ushort_t* __restrict__ ao,
                                                      const ushort_t* __restrict__ w,
                                                      const float* __restrict__ bias,
                                                      float* __restrict__ out) {
    __shared__ __align__(16) ushort_t lds_p[64 * LP];
    __shared__ __align__(16) ushort_t lds_q[128 * LP];
    int tid = threadIdx.x;
    int b = blockIdx.z;
    int p0 = blockIdx.x * 64;
    int c0 = blockIdx.y * 128;
    int lane = tid & 63, wv = tid >> 6;
    int wp = wv & 1, wq = wv >> 1;
    int quad = lane >> 4, l15 = lane & 15;

    f32x4 acc[2][4];
    #pragma unroll
    for (int i = 0; i < 2; ++i)
        #pragma unroll
        for (int jq = 0; jq < 4; ++jq) acc[i][jq] = (f32x4){0.f, 0.f, 0.f, 0.f};

    const ushort_t* abase = ao + ((size_t)b * HEADS) * HW * DD;

    for (int kt = 0; kt < CC / 32; ++kt) {
        __syncthreads();
        {
            int row = tid >> 2, k8 = (tid & 3) * 8;
            uint4_t u = *(const uint4_t*)(abase + ((size_t)kt * HW + p0 + row) * DD + k8);
            *(uint4_t*)&lds_p[row * LP + k8] = u;
        }
        #pragma unroll
        for (int r = 0; r < 2; ++r) {
            int chunk = tid + r * 256;
            int row = chunk >> 2, k8 = (chunk & 3) * 8;
            *(uint4_t*)&lds_q[row * LP + k8] =
                *(const uint4_t*)(w + (size_t)(c0 + row) * CC + kt * 32 + k8);
        }
        __syncthreads();
        bf16x8 afrag[2], bfrag[4];
        #pragma unroll
        for (int i = 0; i < 2; ++i)
            afrag[i] = *(const bf16x8*)&lds_p[(wp * 32 + i * 16 + l15) * LP + quad * 8];
        #pragma unroll
        for (int jq = 0; jq < 4; ++jq)
            bfrag[jq] = *(const bf16x8*)&lds_q[(wq * 64 + jq * 16 + l15) * LP + quad * 8];
        #pragma unroll
        for (int i = 0; i < 2; ++i)
            #pragma unroll
            for (int jq = 0; jq < 4; ++jq)
                acc[i][jq] = __builtin_amdgcn_mfma_f32_16x16x32_bf16(afrag[i], bfrag[jq],
                                                                     acc[i][jq], 0, 0, 0);
    }
    #pragma unroll
    for (int i = 0; i < 2; ++i) {
        int pix = p0 + wp * 32 + i * 16 + quad * 4;
        #pragma unroll
        for (int jq = 0; jq < 4; ++jq) {
            int cch = c0 + wq * 64 + jq * 16 + l15;
            float bz = bias[cch];
            float4 v;
            v.x = acc[i][jq][0] + bz;
            v.y = acc[i][jq][1] + bz;
            v.z = acc[i][jq][2] + bz;
            v.w = acc[i][jq][3] + bz;
            float* dst = out + ((size_t)b * CC + cch) * HW + pix;
            *(float4*)dst = v;
        }
    }
}

// ---------------- GEMM3 fallback (f32 w) ----------------
__global__ __launch_bounds__(256) void proj_gemm_kernel(const ushort_t* __restrict__ ao,
                                                        const float* __restrict__ w,
                                                        const float* __restrict__ bias,
                                                        float* __restrict__ out) {
    __shared__ __align__(16) ushort_t lds_p[64 * LP];
    __shared__ __align__(16) ushort_t lds_q[128 * LP];
    const int K = CC;
    int tid = threadIdx.x;
    int b = blockIdx.z;
    int p0 = blockIdx.x * 64;
    int c0 = blockIdx.y * 128;
    int lane = tid & 63, wv = tid >> 6;
    int wp = wv & 1, wq = wv >> 1;
    int quad = lane >> 4, l15 = lane & 15;

    f32x4 acc[2][4];
    #pragma unroll
    for (int i = 0; i < 2; ++i)
        #pragma unroll
        for (int jq = 0; jq < 4; ++jq) acc[i][jq] = (f32x4){0.f, 0.f, 0.f, 0.f};

    const ushort_t* abase = ao + ((size_t)b * HEADS) * HW * DD;

    for (int kt = 0; kt < K / 32; ++kt) {
        __syncthreads();
        {
            int row = tid >> 2, k8 = (tid & 3) * 8;
            uint4_t u = *(const uint4_t*)(abase + ((size_t)kt * HW + p0 + row) * DD + k8);
            *(uint4_t*)&lds_p[row * LP + k8] = u;
        }
        #pragma unroll
        for (int r = 0; r < 2; ++r) {
            int chunk = tid + r * 256;
            int row = chunk >> 2, k8 = (chunk & 3) * 8;
            const float* src = w + (size_t)(c0 + row) * K + kt * 32 + k8;
            float4 f0 = *(const float4*)src;
            float4 f1 = *(const float4*)(src + 4);
            uint4_t u;
            u[0] = pack2(f0.x, f0.y);
            u[1] = pack2(f0.z, f0.w);
            u[2] = pack2(f1.x, f1.y);
            u[3] = pack2(f1.z, f1.w);
            *(uint4_t*)&lds_q[row * LP + k8] = u;
        }
        __syncthreads();
        bf16x8 afrag[2], bfrag[4];
        #pragma unroll
        for (int i = 0; i < 2; ++i)
            afrag[i] = *(const bf16x8*)&lds_p[(wp * 32 + i * 16 + l15) * LP + quad * 8];
        #pragma unroll
        for (int jq = 0; jq < 4; ++jq)
            bfrag[jq] = *(const bf16x8*)&lds_q[(wq * 64 + jq * 16 + l15) * LP + quad * 8];
        #pragma unroll
        for (int i = 0; i < 2; ++i)
            #pragma unroll
            for (int jq = 0; jq < 4; ++jq)
                acc[i][jq] = __builtin_amdgcn_mfma_f32_16x16x32_bf16(afrag[i], bfrag[jq],
                                                                     acc[i][jq], 0, 0, 0);
    }
    #pragma unroll
    for (int i = 0; i < 2; ++i) {
        int pix = p0 + wp * 32 + i * 16 + quad * 4;
        #pragma unroll
        for (int jq = 0; jq < 4; ++jq) {
            int cch = c0 + wq * 64 + jq * 16 + l15;
            float bz = bias[cch];
            float4 v;
            v.x = acc[i][jq][0] + bz;
            v.y = acc[i][jq][1] + bz;
            v.z = acc[i][jq][2] + bz;
            v.w = acc[i][jq][3] + bz;
            float* dst = out + ((size_t)b * CC + cch) * HW + pix;
            *(float4*)dst = v;
        }
    }
}

extern "C" void kernel_launch(void* const* d_in, const int* in_sizes, int n_in,
                              void* d_out, int out_size, void* d_ws, size_t ws_size,
                              hipStream_t stream) {
    const float* x = (const float*)d_in[0];
    const float* qkv_w = (const float*)d_in[1];
    const float* rpb = (const float*)d_in[2];
    const float* proj_w = (const float*)d_in[3];
    const float* proj_b = (const float*)d_in[4];
    float* out = (float*)d_out;

    size_t need_min = 3 * PLANE * sizeof(ushort_t);                       // 73.5 MB
    size_t need_full = (4 * PLANE + WQ_ELEMS + WP_ELEMS) * sizeof(ushort_t);  // 100 MB

    if (ws_size < need_min) {
        zero_out_f32<<<dim3((int)((OUT_TOT + 255) / 256)), dim3(256), 0, stream>>>(out);
        return;
    }

    ushort_t* qkv = (ushort_t*)d_ws;                 // q/k/v: 3 bf16 planes

    if (ws_size >= need_full) {
        ushort_t* xbf = qkv + 3 * PLANE;             // bf16 x, [b][c][hw]
        ushort_t* wqb = qkv + 4 * PLANE;             // bf16 qkv_w
        ushort_t* wpb = wqb + WQ_ELEMS;              // bf16 proj_w

        int n8x = (int)(PLANE / 8);                  // 1,605,632
        cvt_f32_bf16<<<dim3((n8x + 255) / 256), dim3(256), 0, stream>>>(x, xbf, n8x);
        cvt_f32_bf16<<<dim3((WQ_ELEMS / 8 + 255) / 256), dim3(256), 0, stream>>>(
            qkv_w, wqb, WQ_ELEMS / 8);
        cvt_f32_bf16<<<dim3((WP_ELEMS / 8 + 255) / 256), dim3(256), 0, stream>>>(
            proj_w, wpb, WP_ELEMS / 8);

        qkv_gemm_bf16<<<dim3(49, 6, 8), dim3(256), 0, stream>>>(xbf, wqb, qkv);
        attn_mfma<<<dim3(49, HEADS, BATCH), dim3(256), 0, stream>>>(qkv, rpb);
        proj_gemm_bf16<<<dim3(49, 4, 8), dim3(256), 0, stream>>>(qkv, wpb, proj_b, out);
    } else {
        qkv_gemm_kernel<<<dim3(49, 12, 8), dim3(256), 0, stream>>>(x, qkv_w, qkv);
        attn_mfma<<<dim3(49, HEADS, BATCH), dim3(256), 0, stream>>>(qkv, rpb);
        proj_gemm_kernel<<<dim3(49, 4, 8), dim3(256), 0, stream>>>(qkv, proj_w, proj_b, out);
    }
}

// Round 5
// 268.056 us; speedup vs baseline: 1.8859x; 1.0163x over previous
//
#include <hip/hip_runtime.h>

// NeighborhoodAttention2D: B=8, C=512, H=W=56, heads=16, d=32, KSZ=7
// Round 13: GEMM1 staging fix (95us, VALUBusy 40% vs MfmaUtil 17%, 10.8M conflicts).
//  - prep now TRANSPOSES x to [b][hw][c] bf16 (xpose_cvt, LDS-tiled, XOR-swizzled)
//  - qkv_gemm_bf16 B-staging: 8 scalar ushort loads + 8 packs  ->  ONE uint4 copy
//    (same bank pattern as A staging; 8-lane same-start-bank clustering gone)
//  - attn_mfma (16x16x16 PV, in-reg P), GEMM3, fallbacks unchanged from green r12.

typedef unsigned short ushort_t;
typedef short bf16x8 __attribute__((ext_vector_type(8)));      // 8 bf16 = 4 VGPRs
typedef short bf16x4 __attribute__((ext_vector_type(4)));      // 4 bf16 = 2 VGPRs
typedef float f32x4 __attribute__((ext_vector_type(4)));       // MFMA C/D frag
typedef unsigned int uint4_t __attribute__((ext_vector_type(4)));
typedef unsigned int uint2_t __attribute__((ext_vector_type(2)));

#define BATCH 8
#define HEADS 16
#define HW 3136
#define HH 56
#define DD 32
#define CC 512
#define PLANE ((size_t)BATCH * HEADS * HW * DD)   // 12,845,056 elems (= B*C*HW)
#define OUT_TOT ((size_t)BATCH * CC * HW)
#define LP 40                                      // GEMM LDS row pitch (elems); 80B rows

// attention tile geometry
#define KT 14                                      // key tiles (= patch rows)
#define KP 32                                      // Klds pitch: 64B rows
#define VPP 228                                    // Vlds pitch: 456B rows

#define WQ_ELEMS (1536 * 512)
#define WP_ELEMS (512 * 512)

__device__ __forceinline__ ushort_t f2bf(float f) {
    union { float f; unsigned int i; } v; v.f = f;
    unsigned int r = v.i + 0x7FFFu + ((v.i >> 16) & 1u);   // RNE
    return (ushort_t)(r >> 16);
}
__device__ __forceinline__ unsigned int pack2(float a, float b) {
    return (unsigned int)f2bf(a) | ((unsigned int)f2bf(b) << 16);
}

__device__ __forceinline__ f32x4 mfma16x16x16(bf16x4 a, bf16x4 b, f32x4 c) {
#if __has_builtin(__builtin_amdgcn_mfma_f32_16x16x16bf16_1k)
    return __builtin_amdgcn_mfma_f32_16x16x16bf16_1k(a, b, c, 0, 0, 0);
#else
    f32x4 d;
    asm("v_mfma_f32_16x16x16_bf16 %0, %1, %2, %3" : "=v"(d) : "v"(a), "v"(b), "v"(c));
    return d;
#endif
}

__global__ __launch_bounds__(256) void zero_out_f32(float* __restrict__ out) {
    size_t idx = (size_t)blockIdx.x * 256 + threadIdx.x;
    if (idx < OUT_TOT) out[idx] = 0.f;
}

// ---------------- prep: f32 -> bf16 linear (weights) ----------------
__global__ __launch_bounds__(256) void cvt_f32_bf16(const float* __restrict__ src,
                                                    ushort_t* __restrict__ dst, int n8) {
    int idx = blockIdx.x * 256 + threadIdx.x;
    if (idx >= n8) return;
    const float4* s = (const float4*)src + (size_t)idx * 2;
    float4 f0 = s[0], f1 = s[1];
    uint4_t u;
    u[0] = pack2(f0.x, f0.y);
    u[1] = pack2(f0.z, f0.w);
    u[2] = pack2(f1.x, f1.y);
    u[3] = pack2(f1.z, f1.w);
    *(uint4_t*)(dst + (size_t)idx * 8) = u;
}

// ---------------- prep: x [b][c][hw] f32 -> xbf [b][hw][c] bf16 ----------------
// 64c x 64hw tile per block. LDS T[c][hw ^ SW(c)], SW(c) = ((c>>4)&3)<<4 so that
// phase-2 column reads (c = cq*16+j, lane cq varies) hit 32 distinct banks (2-way).
__global__ __launch_bounds__(256) void xpose_cvt(const float* __restrict__ x,
                                                 ushort_t* __restrict__ xb) {
    __shared__ ushort_t T[64 * 64];                // 8192 B
    int tid = threadIdx.x;
    int hw0 = blockIdx.x * 64;
    int c0 = blockIdx.y * 64;
    int b = blockIdx.z;

    // phase 1: row cr (0..63), hw chunk hq*16
    int cr = tid >> 2, hq = tid & 3;
    const float* src = x + ((size_t)b * CC + c0 + cr) * HW + hw0 + hq * 16;
    float4 f0 = *(const float4*)(src);
    float4 f1 = *(const float4*)(src + 4);
    float4 f2 = *(const float4*)(src + 8);
    float4 f3 = *(const float4*)(src + 12);
    uint4_t u0, u1;
    u0[0] = pack2(f0.x, f0.y); u0[1] = pack2(f0.z, f0.w);
    u0[2] = pack2(f1.x, f1.y); u0[3] = pack2(f1.z, f1.w);
    u1[0] = pack2(f2.x, f2.y); u1[1] = pack2(f2.z, f2.w);
    u1[2] = pack2(f3.x, f3.y); u1[3] = pack2(f3.z, f3.w);
    int sw = ((cr >> 4) & 3) << 4;
    int col0 = (hq * 16) ^ sw;                     // XOR hits bits 4..5 only
    *(uint4_t*)&T[cr * 64 + col0] = u0;
    *(uint4_t*)&T[cr * 64 + col0 + 8] = u1;

    __syncthreads();

    // phase 2: pixel p (0..63), channel chunk cq*16; read columns, write rows
    int p = tid >> 2, cq = tid & 3;
    int pc = p ^ (cq << 4);                        // SW(c) for c in [cq*16, cq*16+16)
    unsigned vv[8];
    #pragma unroll
    for (int j = 0; j < 16; j += 2) {
        unsigned a = T[(cq * 16 + j) * 64 + pc];
        unsigned b2 = T[(cq * 16 + j + 1) * 64 + pc];
        vv[j >> 1] = a | (b2 << 16);
    }
    ushort_t* dst = xb + ((size_t)b * HW + hw0 + p) * CC + c0 + cq * 16;
    uint4_t w0, w1;
    w0[0] = vv[0]; w0[1] = vv[1]; w0[2] = vv[2]; w0[3] = vv[3];
    w1[0] = vv[4]; w1[1] = vv[5]; w1[2] = vv[6]; w1[3] = vv[7];
    *(uint4_t*)&dst[0] = w0;
    *(uint4_t*)&dst[8] = w1;
}

// ---------------- GEMM1 (bf16): qkv^T = wq (1536x512) . xb ([b][hw][c]) ----------
__global__ __launch_bounds__(256) void qkv_gemm_bf16(const ushort_t* __restrict__ xb,
                                                     const ushort_t* __restrict__ w,
                                                     ushort_t* __restrict__ qkv) {
    __shared__ __align__(16) ushort_t lds_p[256 * LP];   // 20480 B
    __shared__ __align__(16) ushort_t lds_q[64 * LP];    //  5120 B
    int tid = threadIdx.x;
    int b = blockIdx.z;
    int n0 = blockIdx.y * 256;
    int p0 = blockIdx.x * 64;
    int lane = tid & 63, wv = tid >> 6;
    int wp = wv & 1, wq = wv >> 1;
    int quad = lane >> 4, l15 = lane & 15;

    f32x4 acc[8][2];
    #pragma unroll
    for (int i = 0; i < 8; ++i)
        #pragma unroll
        for (int jq = 0; jq < 2; ++jq) acc[i][jq] = (f32x4){0.f, 0.f, 0.f, 0.f};

    int spx = tid >> 2, skq = tid & 3;     // B staging: pixel, k-quad

    for (int kt = 0; kt < CC / 32; ++kt) {
        __syncthreads();
        #pragma unroll
        for (int r = 0; r < 4; ++r) {      // A: 256 rows x 32 k, pure uint4 copy
            int chunk = tid + r * 256;
            int row = chunk >> 2, k8 = (chunk & 3) * 8;
            *(uint4_t*)&lds_p[row * LP + k8] =
                *(const uint4_t*)(w + (size_t)(n0 + row) * CC + kt * 32 + k8);
        }
        {                                   // B: xbf [hw][c] -> LDS [pixel][k], uint4 copy
            *(uint4_t*)&lds_q[spx * LP + skq * 8] =
                *(const uint4_t*)(xb + ((size_t)b * HW + p0 + spx) * CC + kt * 32 + skq * 8);
        }
        __syncthreads();
        bf16x8 afrag[8], bfrag[2];
        #pragma unroll
        for (int i = 0; i < 8; ++i)
            afrag[i] = *(const bf16x8*)&lds_p[(wp * 128 + i * 16 + l15) * LP + quad * 8];
        #pragma unroll
        for (int jq = 0; jq < 2; ++jq)
            bfrag[jq] = *(const bf16x8*)&lds_q[(wq * 32 + jq * 16 + l15) * LP + quad * 8];
        #pragma unroll
        for (int i = 0; i < 8; ++i)
            #pragma unroll
            for (int jq = 0; jq < 2; ++jq)
                acc[i][jq] = __builtin_amdgcn_mfma_f32_16x16x32_bf16(afrag[i], bfrag[jq],
                                                                     acc[i][jq], 0, 0, 0);
    }
    const float qscale = 0.17677669529663687f;   // 1/sqrt(32)
    #pragma unroll
    for (int i = 0; i < 8; ++i) {
        int nbase = n0 + wp * 128 + i * 16 + quad * 4;
        int which = nbase >> 9;
        int h = (nbase >> 5) & 15;
        int dch = nbase & 31;
        float sc = (which == 0) ? qscale : 1.0f;
        #pragma unroll
        for (int jq = 0; jq < 2; ++jq) {
            int pix = p0 + wq * 32 + jq * 16 + l15;
            uint2_t v;
            v[0] = pack2(acc[i][jq][0] * sc, acc[i][jq][1] * sc);
            v[1] = pack2(acc[i][jq][2] * sc, acc[i][jq][3] * sc);
            ushort_t* dst = qkv + (size_t)which * PLANE +
                            ((((size_t)b * HEADS + h) * HW + pix) * DD + dch);
            *(uint2_t*)dst = v;
        }
    }
}

// ---------------- GEMM1 fallback (f32 inputs) ----------------
__global__ __launch_bounds__(256) void qkv_gemm_kernel(const float* __restrict__ x,
                                                       const float* __restrict__ w,
                                                       ushort_t* __restrict__ qkv) {
    __shared__ __align__(16) ushort_t lds_p[128 * LP];
    __shared__ __align__(16) ushort_t lds_q[64 * LP];
    const int K = CC;
    int tid = threadIdx.x;
    int b = blockIdx.z;
    int n0 = blockIdx.y * 128;
    int p0 = blockIdx.x * 64;
    int lane = tid & 63, wv = tid >> 6;
    int wp = wv & 1, wq = wv >> 1;
    int quad = lane >> 4, l15 = lane & 15;

    f32x4 acc[4][2];
    #pragma unroll
    for (int i = 0; i < 4; ++i)
        #pragma unroll
        for (int jq = 0; jq < 2; ++jq) acc[i][jq] = (f32x4){0.f, 0.f, 0.f, 0.f};

    int spx = tid & 63;
    int sk8 = (tid >> 6) * 8;

    for (int kt = 0; kt < K / 32; ++kt) {
        __syncthreads();
        #pragma unroll
        for (int r = 0; r < 2; ++r) {
            int chunk = tid + r * 256;
            int row = chunk >> 2, k8 = (chunk & 3) * 8;
            const float* src = w + (size_t)(n0 + row) * K + kt * 32 + k8;
            float4 f0 = *(const float4*)src;
            float4 f1 = *(const float4*)(src + 4);
            uint4_t u;
            u[0] = pack2(f0.x, f0.y);
            u[1] = pack2(f0.z, f0.w);
            u[2] = pack2(f1.x, f1.y);
            u[3] = pack2(f1.z, f1.w);
            *(uint4_t*)&lds_p[row * LP + k8] = u;
        }
        {
            const float* xcol = x + ((size_t)b * CC + kt * 32 + sk8) * HW + p0 + spx;
            float v0 = xcol[0];
            float v1 = xcol[(size_t)HW];
            float v2 = xcol[(size_t)2 * HW];
            float v3 = xcol[(size_t)3 * HW];
            float v4 = xcol[(size_t)4 * HW];
            float v5 = xcol[(size_t)5 * HW];
            float v6 = xcol[(size_t)6 * HW];
            float v7 = xcol[(size_t)7 * HW];
            uint4_t u;
            u[0] = pack2(v0, v1);
            u[1] = pack2(v2, v3);
            u[2] = pack2(v4, v5);
            u[3] = pack2(v6, v7);
            *(uint4_t*)&lds_q[spx * LP + sk8] = u;
        }
        __syncthreads();
        bf16x8 afrag[4], bfrag[2];
        #pragma unroll
        for (int i = 0; i < 4; ++i)
            afrag[i] = *(const bf16x8*)&lds_p[(wp * 64 + i * 16 + l15) * LP + quad * 8];
        #pragma unroll
        for (int jq = 0; jq < 2; ++jq)
            bfrag[jq] = *(const bf16x8*)&lds_q[(wq * 32 + jq * 16 + l15) * LP + quad * 8];
        #pragma unroll
        for (int i = 0; i < 4; ++i)
            #pragma unroll
            for (int jq = 0; jq < 2; ++jq)
                acc[i][jq] = __builtin_amdgcn_mfma_f32_16x16x32_bf16(afrag[i], bfrag[jq],
                                                                     acc[i][jq], 0, 0, 0);
    }
    const float qscale = 0.17677669529663687f;
    #pragma unroll
    for (int i = 0; i < 4; ++i) {
        int nbase = n0 + wp * 64 + i * 16 + quad * 4;
        int which = nbase >> 9;
        int h = (nbase >> 5) & 15;
        int dch = nbase & 31;
        float sc = (which == 0) ? qscale : 1.0f;
        #pragma unroll
        for (int jq = 0; jq < 2; ++jq) {
            int pix = p0 + wq * 32 + jq * 16 + l15;
            uint2_t v;
            v[0] = pack2(acc[i][jq][0] * sc, acc[i][jq][1] * sc);
            v[1] = pack2(acc[i][jq][2] * sc, acc[i][jq][3] * sc);
            ushort_t* dst = qkv + (size_t)which * PLANE +
                            ((((size_t)b * HEADS + h) * HW + pix) * DD + dch);
            *(uint2_t*)dst = v;
        }
    }
}

// ---------------- MFMA attention: one block per (b, h, 8x8 query tile) ----------------
__global__ __launch_bounds__(256, 4) void attn_mfma(ushort_t* __restrict__ qkv,
                                                    const float* __restrict__ rpb) {
    __shared__ __align__(16) ushort_t Klds[224 * KP];        // 14336 B, [kk][d]
    __shared__ __align__(16) ushort_t Vlds[DD * VPP];        // 14592 B, [d][kk]
    __shared__ float rpbl[169];                              //   676 B

    int tid = threadIdx.x;
    int b = blockIdx.z, h = blockIdx.y;
    int tile = blockIdx.x;
    int ti = tile / 7, tj = tile - ti * 7;
    int i0 = ti * 8, j0 = tj * 8;
    int kr0 = min(max(i0 - 3, 0), HH - 14);
    int kc0 = min(max(j0 - 3, 0), HH - 14);

    const ushort_t* qp = qkv + (((size_t)b * HEADS + h) * HW) * DD;
    const ushort_t* kp = qp + PLANE;
    const ushort_t* vp = qp + 2 * PLANE;

    if (tid < 169) rpbl[tid] = rpb[h * 169 + tid];

    // ---- stage K patch: Klds[(u*16+w)][d]; zero pad rows w=14,15
    #pragma unroll
    for (int r = 0; r < 4; ++r) {
        int idx = tid + r * 256;
        if (idx < 784) {                       // 14 rows * 14 keys * 4 octets
            int u = idx / 56;
            int rem = idx - u * 56;
            int w = rem >> 2, d8 = (rem & 3) << 3;
            const ushort_t* src = kp + ((size_t)((kr0 + u) * HH + kc0 + w)) * DD + d8;
            *(uint4_t*)&Klds[(u * 16 + w) * KP + d8] = *(const uint4_t*)src;
        } else if (idx < 896) {                // zero 28 pad rows x 4 octets
            int z = idx - 784;
            int u = z >> 3, rem = z & 7;
            int w = 14 + (rem >> 2), d8 = (rem & 3) << 3;
            *(uint4_t*)&Klds[(u * 16 + w) * KP + d8] = (uint4_t){0, 0, 0, 0};
        }
    }
    // ---- stage V transposed: Vlds[d][kk]; zero pad cols kk%16 in {14,15}
    #pragma unroll
    for (int rr = 0; rr < 2; ++rr) {
        int idx = tid + rr * 256;
        if (idx < 448) {                       // 14 rows * 8 key-pairs * 4 octets
            int u = idx >> 5, rem = idx & 31;
            int pr = rem >> 2, d8 = (rem & 3) << 3;
            int kk0 = u * 16 + pr * 2;
            if (pr < 7) {
                const ushort_t* s0 = vp + ((size_t)((kr0 + u) * HH + kc0 + pr * 2)) * DD + d8;
                uint4_t a = *(const uint4_t*)s0;
                uint4_t c = *(const uint4_t*)(s0 + DD);
                #pragma unroll
                for (int e = 0; e < 4; ++e) {
                    unsigned lo = (a[e] & 0xFFFFu) | (c[e] << 16);
                    unsigned hi = (a[e] >> 16) | (c[e] & 0xFFFF0000u);
                    *(unsigned*)&Vlds[(d8 + 2 * e) * VPP + kk0] = lo;
                    *(unsigned*)&Vlds[(d8 + 2 * e + 1) * VPP + kk0] = hi;
                }
            } else {
                #pragma unroll
                for (int e = 0; e < 8; ++e)
                    *(unsigned*)&Vlds[(d8 + e) * VPP + kk0] = 0;
            }
        }
    }

    int lane = tid & 63, wv = tid >> 6;
    int l15 = lane & 15, quad = lane >> 4;
    int q_idx = wv * 16 + l15;
    int qi = i0 + (q_idx >> 3), qj = j0 + (q_idx & 7);
    int si = min(max(qi - 3, 0), HH - 7);
    int sj = min(max(qj - 3, 0), HH - 7);

    bf16x8 bq = *(const bf16x8*)(qp + ((size_t)(qi * HH + qj)) * DD + quad * 8);

    int jbase = kc0 + quad * 4 - sj;
    int cbase = kc0 + quad * 4 - qj + 6;
    int coff[4];
    bool cok[4];
    #pragma unroll
    for (int r2 = 0; r2 < 4; ++r2) {
        cok[r2] = (unsigned)(jbase + r2) <= 6u;
        coff[r2] = min(max(cbase + r2, 0), 12);
    }

    __syncthreads();

    // ---- QK^T: swapped (A=K, B=Q): lane -> query l15, keys (t*16 + quad*4 + r)
    f32x4 lg[KT];
    f32x4 zf = {0.f, 0.f, 0.f, 0.f};
    #pragma unroll
    for (int t = 0; t < KT; ++t) {
        bf16x8 ak = *(const bf16x8*)&Klds[(t * 16 + l15) * KP + quad * 8];
        lg[t] = __builtin_amdgcn_mfma_f32_16x16x32_bf16(ak, bq, zf, 0, 0, 0);
    }

    int abase = kr0 - qi + 6;
    #pragma unroll
    for (int t = 0; t < KT; ++t) {
        bool rok = (unsigned)(kr0 + t - si) <= 6u;
        int arow = min(max(abase + t, 0), 12);
        const float* br = &rpbl[arow * 13];
        #pragma unroll
        for (int r2 = 0; r2 < 4; ++r2) {
            float bias = br[coff[r2]];
            lg[t][r2] = (rok && cok[r2]) ? lg[t][r2] + bias : -1e30f;
        }
    }

    float m = -1e30f;
    #pragma unroll
    for (int t = 0; t < KT; ++t)
        #pragma unroll
        for (int r2 = 0; r2 < 4; ++r2) m = fmaxf(m, lg[t][r2]);
    m = fmaxf(m, __shfl_xor(m, 16));
    m = fmaxf(m, __shfl_xor(m, 32));
    float s = 0.f;
    #pragma unroll
    for (int t = 0; t < KT; ++t)
        #pragma unroll
        for (int r2 = 0; r2 < 4; ++r2) {
            float e = __expf(lg[t][r2] - m);
            lg[t][r2] = e;
            s += e;
        }
    s += __shfl_xor(s, 16);
    s += __shfl_xor(s, 32);
    float inv = 1.f / s;

    // ---- P -> bf16 in registers (QK D layout == 16x16x16 A layout)
    bf16x4 pb[KT];
    #pragma unroll
    for (int t = 0; t < KT; ++t) {
        union { uint2_t u; bf16x4 v; } cv;
        cv.u[0] = pack2(lg[t][0], lg[t][1]);
        cv.u[1] = pack2(lg[t][2], lg[t][3]);
        pb[t] = cv.v;
    }

    // ---- PV: per 16-key tile, A=P (in-reg), B=V^T tile; 2 d-halves
    f32x4 acc0 = zf, acc1 = zf;
    #pragma unroll
    for (int t = 0; t < KT; ++t) {
        bf16x4 bv0 = *(const bf16x4*)&Vlds[l15 * VPP + t * 16 + quad * 4];
        bf16x4 bv1 = *(const bf16x4*)&Vlds[(16 + l15) * VPP + t * 16 + quad * 4];
        acc0 = mfma16x16x16(pb[t], bv0, acc0);
        acc1 = mfma16x16x16(pb[t], bv1, acc1);
    }

    // ---- normalize in epilogue
    ushort_t* op = qkv + (((size_t)b * HEADS + h) * HW) * DD;
    #pragma unroll
    for (int e = 0; e < 4; ++e) {
        float invq = __shfl(inv, quad * 4 + e);
        int q2 = wv * 16 + quad * 4 + e;
        int pix = (i0 + (q2 >> 3)) * HH + j0 + (q2 & 7);
        op[(size_t)pix * DD + l15] = f2bf(acc0[e] * invq);
        op[(size_t)pix * DD + 16 + l15] = f2bf(acc1[e] * invq);
    }
}

// ---------------- GEMM3 (bf16): y = attn_out . wpb^T + b; OUT f32 ----------------
__global__ __launch_bounds__(256) void proj_gemm_bf16(const ushort_t* __restrict__ ao,
                                                      const ushort_t* __restrict__ w,
                                                      const float* __restrict__ bias,
                                                      float* __restrict__ out) {
    __shared__ __align__(16) ushort_t lds_p[64 * LP];
    __shared__ __align__(16) ushort_t lds_q[128 * LP];
    int tid = threadIdx.x;
    int b = blockIdx.z;
    int p0 = blockIdx.x * 64;
    int c0 = blockIdx.y * 128;
    int lane = tid & 63, wv = tid >> 6;
    int wp = wv & 1, wq = wv >> 1;
    int quad = lane >> 4, l15 = lane & 15;

    f32x4 acc[2][4];
    #pragma unroll
    for (int i = 0; i < 2; ++i)
        #pragma unroll
        for (int jq = 0; jq < 4; ++jq) acc[i][jq] = (f32x4){0.f, 0.f, 0.f, 0.f};

    const ushort_t* abase = ao + ((size_t)b * HEADS) * HW * DD;

    for (int kt = 0; kt < CC / 32; ++kt) {
        __syncthreads();
        {
            int row = tid >> 2, k8 = (tid & 3) * 8;
            uint4_t u = *(const uint4_t*)(abase + ((size_t)kt * HW + p0 + row) * DD + k8);
            *(uint4_t*)&lds_p[row * LP + k8] = u;
        }
        #pragma unroll
        for (int r = 0; r < 2; ++r) {
            int chunk = tid + r * 256;
            int row = chunk >> 2, k8 = (chunk & 3) * 8;
            *(uint4_t*)&lds_q[row * LP + k8] =
                *(const uint4_t*)(w + (size_t)(c0 + row) * CC + kt * 32 + k8);
        }
        __syncthreads();
        bf16x8 afrag[2], bfrag[4];
        #pragma unroll
        for (int i = 0; i < 2; ++i)
            afrag[i] = *(const bf16x8*)&lds_p[(wp * 32 + i * 16 + l15) * LP + quad * 8];
        #pragma unroll
        for (int jq = 0; jq < 4; ++jq)
            bfrag[jq] = *(const bf16x8*)&lds_q[(wq * 64 + jq * 16 + l15) * LP + quad * 8];
        #pragma unroll
        for (int i = 0; i < 2; ++i)
            #pragma unroll
            for (int jq = 0; jq < 4; ++jq)
                acc[i][jq] = __builtin_amdgcn_mfma_f32_16x16x32_bf16(afrag[i], bfrag[jq],
                                                                     acc[i][jq], 0, 0, 0);
    }
    #pragma unroll
    for (int i = 0; i < 2; ++i) {
        int pix = p0 + wp * 32 + i * 16 + quad * 4;
        #pragma unroll
        for (int jq = 0; jq < 4; ++jq) {
            int cch = c0 + wq * 64 + jq * 16 + l15;
            float bz = bias[cch];
            float4 v;
            v.x = acc[i][jq][0] + bz;
            v.y = acc[i][jq][1] + bz;
            v.z = acc[i][jq][2] + bz;
            v.w = acc[i][jq][3] + bz;
            float* dst = out + ((size_t)b * CC + cch) * HW + pix;
            *(float4*)dst = v;
        }
    }
}

// ---------------- GEMM3 fallback (f32 w) ----------------
__global__ __launch_bounds__(256) void proj_gemm_kernel(const ushort_t* __restrict__ ao,
                                                        const float* __restrict__ w,
                                                        const float* __restrict__ bias,
                                                        float* __restrict__ out) {
    __shared__ __align__(16) ushort_t lds_p[64 * LP];
    __shared__ __align__(16) ushort_t lds_q[128 * LP];
    const int K = CC;
    int tid = threadIdx.x;
    int b = blockIdx.z;
    int p0 = blockIdx.x * 64;
    int c0 = blockIdx.y * 128;
    int lane = tid & 63, wv = tid >> 6;
    int wp = wv & 1, wq = wv >> 1;
    int quad = lane >> 4, l15 = lane & 15;

    f32x4 acc[2][4];
    #pragma unroll
    for (int i = 0; i < 2; ++i)
        #pragma unroll
        for (int jq = 0; jq < 4; ++jq) acc[i][jq] = (f32x4){0.f, 0.f, 0.f, 0.f};

    const ushort_t* abase = ao + ((size_t)b * HEADS) * HW * DD;

    for (int kt = 0; kt < K / 32; ++kt) {
        __syncthreads();
        {
            int row = tid >> 2, k8 = (tid & 3) * 8;
            uint4_t u = *(const uint4_t*)(abase + ((size_t)kt * HW + p0 + row) * DD + k8);
            *(uint4_t*)&lds_p[row * LP + k8] = u;
        }
        #pragma unroll
        for (int r = 0; r < 2; ++r) {
            int chunk = tid + r * 256;
            int row = chunk >> 2, k8 = (chunk & 3) * 8;
            const float* src = w + (size_t)(c0 + row) * K + kt * 32 + k8;
            float4 f0 = *(const float4*)src;
            float4 f1 = *(const float4*)(src + 4);
            uint4_t u;
            u[0] = pack2(f0.x, f0.y);
            u[1] = pack2(f0.z, f0.w);
            u[2] = pack2(f1.x, f1.y);
            u[3] = pack2(f1.z, f1.w);
            *(uint4_t*)&lds_q[row * LP + k8] = u;
        }
        __syncthreads();
        bf16x8 afrag[2], bfrag[4];
        #pragma unroll
        for (int i = 0; i < 2; ++i)
            afrag[i] = *(const bf16x8*)&lds_p[(wp * 32 + i * 16 + l15) * LP + quad * 8];
        #pragma unroll
        for (int jq = 0; jq < 4; ++jq)
            bfrag[jq] = *(const bf16x8*)&lds_q[(wq * 64 + jq * 16 + l15) * LP + quad * 8];
        #pragma unroll
        for (int i = 0; i < 2; ++i)
            #pragma unroll
            for (int jq = 0; jq < 4; ++jq)
                acc[i][jq] = __builtin_amdgcn_mfma_f32_16x16x32_bf16(afrag[i], bfrag[jq],
                                                                     acc[i][jq], 0, 0, 0);
    }
    #pragma unroll
    for (int i = 0; i < 2; ++i) {
        int pix = p0 + wp * 32 + i * 16 + quad * 4;
        #pragma unroll
        for (int jq = 0; jq < 4; ++jq) {
            int cch = c0 + wq * 64 + jq * 16 + l15;
            float bz = bias[cch];
            float4 v;
            v.x = acc[i][jq][0] + bz;
            v.y = acc[i][jq][1] + bz;
            v.z = acc[i][jq][2] + bz;
            v.w = acc[i][jq][3] + bz;
            float* dst = out + ((size_t)b * CC + cch) * HW + pix;
            *(float4*)dst = v;
        }
    }
}

extern "C" void kernel_launch(void* const* d_in, const int* in_sizes, int n_in,
                              void* d_out, int out_size, void* d_ws, size_t ws_size,
                              hipStream_t stream) {
    const float* x = (const float*)d_in[0];
    const float* qkv_w = (const float*)d_in[1];
    const float* rpb = (const float*)d_in[2];
    const float* proj_w = (const float*)d_in[3];
    const float* proj_b = (const float*)d_in[4];
    float* out = (float*)d_out;

    size_t need_min = 3 * PLANE * sizeof(ushort_t);                       // 73.5 MB
    size_t need_full = (4 * PLANE + WQ_ELEMS + WP_ELEMS) * sizeof(ushort_t);  // 100 MB

    if (ws_size < need_min) {
        zero_out_f32<<<dim3((int)((OUT_TOT + 255) / 256)), dim3(256), 0, stream>>>(out);
        return;
    }

    ushort_t* qkv = (ushort_t*)d_ws;                 // q/k/v: 3 bf16 planes

    if (ws_size >= need_full) {
        ushort_t* xbf = qkv + 3 * PLANE;             // bf16 x, [b][hw][c] (TRANSPOSED)
        ushort_t* wqb = qkv + 4 * PLANE;             // bf16 qkv_w
        ushort_t* wpb = wqb + WQ_ELEMS;              // bf16 proj_w

        xpose_cvt<<<dim3(49, 8, 8), dim3(256), 0, stream>>>(x, xbf);
        cvt_f32_bf16<<<dim3((WQ_ELEMS / 8 + 255) / 256), dim3(256), 0, stream>>>(
            qkv_w, wqb, WQ_ELEMS / 8);
        cvt_f32_bf16<<<dim3((WP_ELEMS / 8 + 255) / 256), dim3(256), 0, stream>>>(
            proj_w, wpb, WP_ELEMS / 8);

        qkv_gemm_bf16<<<dim3(49, 6, 8), dim3(256), 0, stream>>>(xbf, wqb, qkv);
        attn_mfma<<<dim3(49, HEADS, BATCH), dim3(256), 0, stream>>>(qkv, rpb);
        proj_gemm_bf16<<<dim3(49, 4, 8), dim3(256), 0, stream>>>(qkv, wpb, proj_b, out);
    } else {
        qkv_gemm_kernel<<<dim3(49, 12, 8), dim3(256), 0, stream>>>(x, qkv_w, qkv);
        attn_mfma<<<dim3(49, HEADS, BATCH), dim3(256), 0, stream>>>(qkv, rpb);
        proj_gemm_kernel<<<dim3(49, 4, 8), dim3(256), 0, stream>>>(qkv, proj_w, proj_b, out);
    }
}

// Round 7
// 263.056 us; speedup vs baseline: 1.9218x; 1.0190x over previous
//
#include <hip/hip_runtime.h>

// NeighborhoodAttention2D: B=8, C=512, H=W=56, heads=16, d=32, KSZ=7
// Round 15: identical to round 14 (container failed twice = infra signature,
// same as round 1 which then passed green on resubmit). gload_lds staging
// re-audited: wave-linear dest, T21 involution swizzle, bounds, alignment OK.
//  - GEMM1/GEMM3 staging via global_load_lds width=16 (m93->m97 lever).
//  - LDS pitch 32 (linear); XOR swizzle ch^=(row>>1)&3 on GLOBAL source + read.
//  - attn_mfma, xpose_cvt, cvt, fallbacks unchanged from green r13.

typedef unsigned short ushort_t;
typedef short bf16x8 __attribute__((ext_vector_type(8)));      // 8 bf16 = 4 VGPRs
typedef short bf16x4 __attribute__((ext_vector_type(4)));      // 4 bf16 = 2 VGPRs
typedef float f32x4 __attribute__((ext_vector_type(4)));       // MFMA C/D frag
typedef unsigned int uint4_t __attribute__((ext_vector_type(4)));
typedef unsigned int uint2_t __attribute__((ext_vector_type(2)));

#define BATCH 8
#define HEADS 16
#define HW 3136
#define HH 56
#define DD 32
#define CC 512
#define PLANE ((size_t)BATCH * HEADS * HW * DD)   // 12,845,056 elems (= B*C*HW)
#define OUT_TOT ((size_t)BATCH * CC * HW)
#define LP 40                                      // fallback-GEMM LDS pitch
#define LPG 32                                     // gload_lds GEMM pitch (linear rows)

// attention tile geometry
#define KT 14
#define KP 32
#define VPP 228

#define WQ_ELEMS (1536 * 512)
#define WP_ELEMS (512 * 512)

__device__ __forceinline__ ushort_t f2bf(float f) {
    union { float f; unsigned int i; } v; v.f = f;
    unsigned int r = v.i + 0x7FFFu + ((v.i >> 16) & 1u);   // RNE
    return (ushort_t)(r >> 16);
}
__device__ __forceinline__ unsigned int pack2(float a, float b) {
    return (unsigned int)f2bf(a) | ((unsigned int)f2bf(b) << 16);
}

__device__ __forceinline__ f32x4 mfma16x16x16(bf16x4 a, bf16x4 b, f32x4 c) {
#if __has_builtin(__builtin_amdgcn_mfma_f32_16x16x16bf16_1k)
    return __builtin_amdgcn_mfma_f32_16x16x16bf16_1k(a, b, c, 0, 0, 0);
#else
    f32x4 d;
    asm("v_mfma_f32_16x16x16_bf16 %0, %1, %2, %3" : "=v"(d) : "v"(a), "v"(b), "v"(c));
    return d;
#endif
}

// async global->LDS, 16B per lane; lds dest must be wave-linear (base + lane*16)
__device__ __forceinline__ void gload16(const ushort_t* g, ushort_t* l) {
    __builtin_amdgcn_global_load_lds(
        (const __attribute__((address_space(1))) unsigned int*)g,
        (__attribute__((address_space(3))) unsigned int*)l, 16, 0, 0);
}

__global__ __launch_bounds__(256) void zero_out_f32(float* __restrict__ out) {
    size_t idx = (size_t)blockIdx.x * 256 + threadIdx.x;
    if (idx < OUT_TOT) out[idx] = 0.f;
}

// ---------------- prep: f32 -> bf16 linear (weights) ----------------
__global__ __launch_bounds__(256) void cvt_f32_bf16(const float* __restrict__ src,
                                                    ushort_t* __restrict__ dst, int n8) {
    int idx = blockIdx.x * 256 + threadIdx.x;
    if (idx >= n8) return;
    const float4* s = (const float4*)src + (size_t)idx * 2;
    float4 f0 = s[0], f1 = s[1];
    uint4_t u;
    u[0] = pack2(f0.x, f0.y);
    u[1] = pack2(f0.z, f0.w);
    u[2] = pack2(f1.x, f1.y);
    u[3] = pack2(f1.z, f1.w);
    *(uint4_t*)(dst + (size_t)idx * 8) = u;
}

// ---------------- prep: x [b][c][hw] f32 -> xbf [b][hw][c] bf16 ----------------
__global__ __launch_bounds__(256) void xpose_cvt(const float* __restrict__ x,
                                                 ushort_t* __restrict__ xb) {
    __shared__ ushort_t T[64 * 64];                // 8192 B
    int tid = threadIdx.x;
    int hw0 = blockIdx.x * 64;
    int c0 = blockIdx.y * 64;
    int b = blockIdx.z;

    int cr = tid >> 2, hq = tid & 3;
    const float* src = x + ((size_t)b * CC + c0 + cr) * HW + hw0 + hq * 16;
    float4 f0 = *(const float4*)(src);
    float4 f1 = *(const float4*)(src + 4);
    float4 f2 = *(const float4*)(src + 8);
    float4 f3 = *(const float4*)(src + 12);
    uint4_t u0, u1;
    u0[0] = pack2(f0.x, f0.y); u0[1] = pack2(f0.z, f0.w);
    u0[2] = pack2(f1.x, f1.y); u0[3] = pack2(f1.z, f1.w);
    u1[0] = pack2(f2.x, f2.y); u1[1] = pack2(f2.z, f2.w);
    u1[2] = pack2(f3.x, f3.y); u1[3] = pack2(f3.z, f3.w);
    int sw = ((cr >> 4) & 3) << 4;
    int col0 = (hq * 16) ^ sw;
    *(uint4_t*)&T[cr * 64 + col0] = u0;
    *(uint4_t*)&T[cr * 64 + col0 + 8] = u1;

    __syncthreads();

    int p = tid >> 2, cq = tid & 3;
    int pc = p ^ (cq << 4);
    unsigned vv[8];
    #pragma unroll
    for (int j = 0; j < 16; j += 2) {
        unsigned a = T[(cq * 16 + j) * 64 + pc];
        unsigned b2 = T[(cq * 16 + j + 1) * 64 + pc];
        vv[j >> 1] = a | (b2 << 16);
    }
    ushort_t* dst = xb + ((size_t)b * HW + hw0 + p) * CC + c0 + cq * 16;
    uint4_t w0, w1;
    w0[0] = vv[0]; w0[1] = vv[1]; w0[2] = vv[2]; w0[3] = vv[3];
    w1[0] = vv[4]; w1[1] = vv[5]; w1[2] = vv[6]; w1[3] = vv[7];
    *(uint4_t*)&dst[0] = w0;
    *(uint4_t*)&dst[8] = w1;
}

// ---------------- GEMM1 (bf16): qkv^T = wq (1536x512) . xb ([b][hw][c]) ----------
// gload_lds staging: linear LDS (LPG=32), swizzled global source ch^=(row>>1)&3.
__global__ __launch_bounds__(256) void qkv_gemm_bf16(const ushort_t* __restrict__ xb,
                                                     const ushort_t* __restrict__ w,
                                                     ushort_t* __restrict__ qkv) {
    __shared__ __align__(16) ushort_t lds_p[256 * LPG];   // 16384 B
    __shared__ __align__(16) ushort_t lds_q[64 * LPG];    //  4096 B
    int tid = threadIdx.x;
    int b = blockIdx.z;
    int n0 = blockIdx.y * 256;
    int p0 = blockIdx.x * 64;
    int lane = tid & 63, wv = tid >> 6;
    int wp = wv & 1, wq = wv >> 1;
    int quad = lane >> 4, l15 = lane & 15;

    f32x4 acc[8][2];
    #pragma unroll
    for (int i = 0; i < 8; ++i)
        #pragma unroll
        for (int jq = 0; jq < 2; ++jq) acc[i][jq] = (f32x4){0.f, 0.f, 0.f, 0.f};

    int swz = (l15 >> 1) & 3;                  // fragment-read swizzle (row->chunk)
    int cha = (quad ^ swz) * 8;                // swizzled k-octet for frag reads

    for (int kt = 0; kt < CC / 32; ++kt) {
        __syncthreads();
        #pragma unroll
        for (int r = 0; r < 4; ++r) {          // A: 1024 chunks, 4/thread
            int c = r * 256 + tid;
            int row = c >> 2;
            int kch = (c & 3) ^ ((c >> 3) & 3);
            gload16(w + (size_t)(n0 + row) * CC + kt * 32 + kch * 8, &lds_p[c * 8]);
        }
        {                                       // B: 256 chunks, 1/thread
            int c = tid;
            int row = c >> 2;
            int kch = (c & 3) ^ ((c >> 3) & 3);
            gload16(xb + ((size_t)b * HW + p0 + row) * CC + kt * 32 + kch * 8,
                    &lds_q[c * 8]);
        }
        __syncthreads();                        // compiler drains vmcnt before barrier
        bf16x8 afrag[8], bfrag[2];
        #pragma unroll
        for (int i = 0; i < 8; ++i)
            afrag[i] = *(const bf16x8*)&lds_p[(wp * 128 + i * 16 + l15) * LPG + cha];
        #pragma unroll
        for (int jq = 0; jq < 2; ++jq)
            bfrag[jq] = *(const bf16x8*)&lds_q[(wq * 32 + jq * 16 + l15) * LPG + cha];
        #pragma unroll
        for (int i = 0; i < 8; ++i)
            #pragma unroll
            for (int jq = 0; jq < 2; ++jq)
                acc[i][jq] = __builtin_amdgcn_mfma_f32_16x16x32_bf16(afrag[i], bfrag[jq],
                                                                     acc[i][jq], 0, 0, 0);
    }
    const float qscale = 0.17677669529663687f;   // 1/sqrt(32)
    #pragma unroll
    for (int i = 0; i < 8; ++i) {
        int nbase = n0 + wp * 128 + i * 16 + quad * 4;
        int which = nbase >> 9;
        int h = (nbase >> 5) & 15;
        int dch = nbase & 31;
        float sc = (which == 0) ? qscale : 1.0f;
        #pragma unroll
        for (int jq = 0; jq < 2; ++jq) {
            int pix = p0 + wq * 32 + jq * 16 + l15;
            uint2_t v;
            v[0] = pack2(acc[i][jq][0] * sc, acc[i][jq][1] * sc);
            v[1] = pack2(acc[i][jq][2] * sc, acc[i][jq][3] * sc);
            ushort_t* dst = qkv + (size_t)which * PLANE +
                            ((((size_t)b * HEADS + h) * HW + pix) * DD + dch);
            *(uint2_t*)dst = v;
        }
    }
}

// ---------------- GEMM1 fallback (f32 inputs) ----------------
__global__ __launch_bounds__(256) void qkv_gemm_kernel(const float* __restrict__ x,
                                                       const float* __restrict__ w,
                                                       ushort_t* __restrict__ qkv) {
    __shared__ __align__(16) ushort_t lds_p[128 * LP];
    __shared__ __align__(16) ushort_t lds_q[64 * LP];
    const int K = CC;
    int tid = threadIdx.x;
    int b = blockIdx.z;
    int n0 = blockIdx.y * 128;
    int p0 = blockIdx.x * 64;
    int lane = tid & 63, wv = tid >> 6;
    int wp = wv & 1, wq = wv >> 1;
    int quad = lane >> 4, l15 = lane & 15;

    f32x4 acc[4][2];
    #pragma unroll
    for (int i = 0; i < 4; ++i)
        #pragma unroll
        for (int jq = 0; jq < 2; ++jq) acc[i][jq] = (f32x4){0.f, 0.f, 0.f, 0.f};

    int spx = tid & 63;
    int sk8 = (tid >> 6) * 8;

    for (int kt = 0; kt < K / 32; ++kt) {
        __syncthreads();
        #pragma unroll
        for (int r = 0; r < 2; ++r) {
            int chunk = tid + r * 256;
            int row = chunk >> 2, k8 = (chunk & 3) * 8;
            const float* src = w + (size_t)(n0 + row) * K + kt * 32 + k8;
            float4 f0 = *(const float4*)src;
            float4 f1 = *(const float4*)(src + 4);
            uint4_t u;
            u[0] = pack2(f0.x, f0.y);
            u[1] = pack2(f0.z, f0.w);
            u[2] = pack2(f1.x, f1.y);
            u[3] = pack2(f1.z, f1.w);
            *(uint4_t*)&lds_p[row * LP + k8] = u;
        }
        {
            const float* xcol = x + ((size_t)b * CC + kt * 32 + sk8) * HW + p0 + spx;
            float v0 = xcol[0];
            float v1 = xcol[(size_t)HW];
            float v2 = xcol[(size_t)2 * HW];
            float v3 = xcol[(size_t)3 * HW];
            float v4 = xcol[(size_t)4 * HW];
            float v5 = xcol[(size_t)5 * HW];
            float v6 = xcol[(size_t)6 * HW];
            float v7 = xcol[(size_t)7 * HW];
            uint4_t u;
            u[0] = pack2(v0, v1);
            u[1] = pack2(v2, v3);
            u[2] = pack2(v4, v5);
            u[3] = pack2(v6, v7);
            *(uint4_t*)&lds_q[spx * LP + sk8] = u;
        }
        __syncthreads();
        bf16x8 afrag[4], bfrag[2];
        #pragma unroll
        for (int i = 0; i < 4; ++i)
            afrag[i] = *(const bf16x8*)&lds_p[(wp * 64 + i * 16 + l15) * LP + quad * 8];
        #pragma unroll
        for (int jq = 0; jq < 2; ++jq)
            bfrag[jq] = *(const bf16x8*)&lds_q[(wq * 32 + jq * 16 + l15) * LP + quad * 8];
        #pragma unroll
        for (int i = 0; i < 4; ++i)
            #pragma unroll
            for (int jq = 0; jq < 2; ++jq)
                acc[i][jq] = __builtin_amdgcn_mfma_f32_16x16x32_bf16(afrag[i], bfrag[jq],
                                                                     acc[i][jq], 0, 0, 0);
    }
    const float qscale = 0.17677669529663687f;
    #pragma unroll
    for (int i = 0; i < 4; ++i) {
        int nbase = n0 + wp * 64 + i * 16 + quad * 4;
        int which = nbase >> 9;
        int h = (nbase >> 5) & 15;
        int dch = nbase & 31;
        float sc = (which == 0) ? qscale : 1.0f;
        #pragma unroll
        for (int jq = 0; jq < 2; ++jq) {
            int pix = p0 + wq * 32 + jq * 16 + l15;
            uint2_t v;
            v[0] = pack2(acc[i][jq][0] * sc, acc[i][jq][1] * sc);
            v[1] = pack2(acc[i][jq][2] * sc, acc[i][jq][3] * sc);
            ushort_t* dst = qkv + (size_t)which * PLANE +
                            ((((size_t)b * HEADS + h) * HW + pix) * DD + dch);
            *(uint2_t*)dst = v;
        }
    }
}

// ---------------- MFMA attention: one block per (b, h, 8x8 query tile) ----------------
__global__ __launch_bounds__(256, 4) void attn_mfma(ushort_t* __restrict__ qkv,
                                                    const float* __restrict__ rpb) {
    __shared__ __align__(16) ushort_t Klds[224 * KP];        // 14336 B, [kk][d]
    __shared__ __align__(16) ushort_t Vlds[DD * VPP];        // 14592 B, [d][kk]
    __shared__ float rpbl[169];                              //   676 B

    int tid = threadIdx.x;
    int b = blockIdx.z, h = blockIdx.y;
    int tile = blockIdx.x;
    int ti = tile / 7, tj = tile - ti * 7;
    int i0 = ti * 8, j0 = tj * 8;
    int kr0 = min(max(i0 - 3, 0), HH - 14);
    int kc0 = min(max(j0 - 3, 0), HH - 14);

    const ushort_t* qp = qkv + (((size_t)b * HEADS + h) * HW) * DD;
    const ushort_t* kp = qp + PLANE;
    const ushort_t* vp = qp + 2 * PLANE;

    if (tid < 169) rpbl[tid] = rpb[h * 169 + tid];

    #pragma unroll
    for (int r = 0; r < 4; ++r) {
        int idx = tid + r * 256;
        if (idx < 784) {
            int u = idx / 56;
            int rem = idx - u * 56;
            int w = rem >> 2, d8 = (rem & 3) << 3;
            const ushort_t* src = kp + ((size_t)((kr0 + u) * HH + kc0 + w)) * DD + d8;
            *(uint4_t*)&Klds[(u * 16 + w) * KP + d8] = *(const uint4_t*)src;
        } else if (idx < 896) {
            int z = idx - 784;
            int u = z >> 3, rem = z & 7;
            int w = 14 + (rem >> 2), d8 = (rem & 3) << 3;
            *(uint4_t*)&Klds[(u * 16 + w) * KP + d8] = (uint4_t){0, 0, 0, 0};
        }
    }
    #pragma unroll
    for (int rr = 0; rr < 2; ++rr) {
        int idx = tid + rr * 256;
        if (idx < 448) {
            int u = idx >> 5, rem = idx & 31;
            int pr = rem >> 2, d8 = (rem & 3) << 3;
            int kk0 = u * 16 + pr * 2;
            if (pr < 7) {
                const ushort_t* s0 = vp + ((size_t)((kr0 + u) * HH + kc0 + pr * 2)) * DD + d8;
                uint4_t a = *(const uint4_t*)s0;
                uint4_t c = *(const uint4_t*)(s0 + DD);
                #pragma unroll
                for (int e = 0; e < 4; ++e) {
                    unsigned lo = (a[e] & 0xFFFFu) | (c[e] << 16);
                    unsigned hi = (a[e] >> 16) | (c[e] & 0xFFFF0000u);
                    *(unsigned*)&Vlds[(d8 + 2 * e) * VPP + kk0] = lo;
                    *(unsigned*)&Vlds[(d8 + 2 * e + 1) * VPP + kk0] = hi;
                }
            } else {
                #pragma unroll
                for (int e = 0; e < 8; ++e)
                    *(unsigned*)&Vlds[(d8 + e) * VPP + kk0] = 0;
            }
        }
    }

    int lane = tid & 63, wv = tid >> 6;
    int l15 = lane & 15, quad = lane >> 4;
    int q_idx = wv * 16 + l15;
    int qi = i0 + (q_idx >> 3), qj = j0 + (q_idx & 7);
    int si = min(max(qi - 3, 0), HH - 7);
    int sj = min(max(qj - 3, 0), HH - 7);

    bf16x8 bq = *(const bf16x8*)(qp + ((size_t)(qi * HH + qj)) * DD + quad * 8);

    int jbase = kc0 + quad * 4 - sj;
    int cbase = kc0 + quad * 4 - qj + 6;
    int coff[4];
    bool cok[4];
    #pragma unroll
    for (int r2 = 0; r2 < 4; ++r2) {
        cok[r2] = (unsigned)(jbase + r2) <= 6u;
        coff[r2] = min(max(cbase + r2, 0), 12);
    }

    __syncthreads();

    f32x4 lg[KT];
    f32x4 zf = {0.f, 0.f, 0.f, 0.f};
    #pragma unroll
    for (int t = 0; t < KT; ++t) {
        bf16x8 ak = *(const bf16x8*)&Klds[(t * 16 + l15) * KP + quad * 8];
        lg[t] = __builtin_amdgcn_mfma_f32_16x16x32_bf16(ak, bq, zf, 0, 0, 0);
    }

    int abase = kr0 - qi + 6;
    #pragma unroll
    for (int t = 0; t < KT; ++t) {
        bool rok = (unsigned)(kr0 + t - si) <= 6u;
        int arow = min(max(abase + t, 0), 12);
        const float* br = &rpbl[arow * 13];
        #pragma unroll
        for (int r2 = 0; r2 < 4; ++r2) {
            float bias = br[coff[r2]];
            lg[t][r2] = (rok && cok[r2]) ? lg[t][r2] + bias : -1e30f;
        }
    }

    float m = -1e30f;
    #pragma unroll
    for (int t = 0; t < KT; ++t)
        #pragma unroll
        for (int r2 = 0; r2 < 4; ++r2) m = fmaxf(m, lg[t][r2]);
    m = fmaxf(m, __shfl_xor(m, 16));
    m = fmaxf(m, __shfl_xor(m, 32));
    float s = 0.f;
    #pragma unroll
    for (int t = 0; t < KT; ++t)
        #pragma unroll
        for (int r2 = 0; r2 < 4; ++r2) {
            float e = __expf(lg[t][r2] - m);
            lg[t][r2] = e;
            s += e;
        }
    s += __shfl_xor(s, 16);
    s += __shfl_xor(s, 32);
    float inv = 1.f / s;

    bf16x4 pb[KT];
    #pragma unroll
    for (int t = 0; t < KT; ++t) {
        union { uint2_t u; bf16x4 v; } cv;
        cv.u[0] = pack2(lg[t][0], lg[t][1]);
        cv.u[1] = pack2(lg[t][2], lg[t][3]);
        pb[t] = cv.v;
    }

    f32x4 acc0 = zf, acc1 = zf;
    #pragma unroll
    for (int t = 0; t < KT; ++t) {
        bf16x4 bv0 = *(const bf16x4*)&Vlds[l15 * VPP + t * 16 + quad * 4];
        bf16x4 bv1 = *(const bf16x4*)&Vlds[(16 + l15) * VPP + t * 16 + quad * 4];
        acc0 = mfma16x16x16(pb[t], bv0, acc0);
        acc1 = mfma16x16x16(pb[t], bv1, acc1);
    }

    ushort_t* op = qkv + (((size_t)b * HEADS + h) * HW) * DD;
    #pragma unroll
    for (int e = 0; e < 4; ++e) {
        float invq = __shfl(inv, quad * 4 + e);
        int q2 = wv * 16 + quad * 4 + e;
        int pix = (i0 + (q2 >> 3)) * HH + j0 + (q2 & 7);
        op[(size_t)pix * DD + l15] = f2bf(acc0[e] * invq);
        op[(size_t)pix * DD + 16 + l15] = f2bf(acc1[e] * invq);
    }
}

// ---------------- GEMM3 (bf16): y = attn_out . wpb^T + b; OUT f32 ----------------
// gload_lds staging, linear LDS (LPG), swizzled source; swizzled frag reads.
__global__ __launch_bounds__(256) void proj_gemm_bf16(const ushort_t* __restrict__ ao,
                                                      const ushort_t* __restrict__ w,
                                                      const float* __restrict__ bias,
                                                      float* __restrict__ out) {
    __shared__ __align__(16) ushort_t lds_p[64 * LPG];    // 4096 B
    __shared__ __align__(16) ushort_t lds_q[128 * LPG];   // 8192 B
    int tid = threadIdx.x;
    int b = blockIdx.z;
    int p0 = blockIdx.x * 64;
    int c0 = blockIdx.y * 128;
    int lane = tid & 63, wv = tid >> 6;
    int wp = wv & 1, wq = wv >> 1;
    int quad = lane >> 4, l15 = lane & 15;

    f32x4 acc[2][4];
    #pragma unroll
    for (int i = 0; i < 2; ++i)
        #pragma unroll
        for (int jq = 0; jq < 4; ++jq) acc[i][jq] = (f32x4){0.f, 0.f, 0.f, 0.f};

    const ushort_t* abase = ao + ((size_t)b * HEADS) * HW * DD;
    int swz = (l15 >> 1) & 3;
    int cha = (quad ^ swz) * 8;

    for (int kt = 0; kt < CC / 32; ++kt) {
        __syncthreads();
        {                                       // A: 256 chunks (64 pixel rows)
            int c = tid;
            int row = c >> 2;
            int kch = (c & 3) ^ ((c >> 3) & 3);
            gload16(abase + ((size_t)kt * HW + p0 + row) * DD + kch * 8, &lds_p[c * 8]);
        }
        #pragma unroll
        for (int r = 0; r < 2; ++r) {           // B: 512 chunks (128 weight rows)
            int c = r * 256 + tid;
            int row = c >> 2;
            int kch = (c & 3) ^ ((c >> 3) & 3);
            gload16(w + (size_t)(c0 + row) * CC + kt * 32 + kch * 8, &lds_q[c * 8]);
        }
        __syncthreads();
        bf16x8 afrag[2], bfrag[4];
        #pragma unroll
        for (int i = 0; i < 2; ++i)
            afrag[i] = *(const bf16x8*)&lds_p[(wp * 32 + i * 16 + l15) * LPG + cha];
        #pragma unroll
        for (int jq = 0; jq < 4; ++jq)
            bfrag[jq] = *(const bf16x8*)&lds_q[(wq * 64 + jq * 16 + l15) * LPG + cha];
        #pragma unroll
        for (int i = 0; i < 2; ++i)
            #pragma unroll
            for (int jq = 0; jq < 4; ++jq)
                acc[i][jq] = __builtin_amdgcn_mfma_f32_16x16x32_bf16(afrag[i], bfrag[jq],
                                                                     acc[i][jq], 0, 0, 0);
    }
    #pragma unroll
    for (int i = 0; i < 2; ++i) {
        int pix = p0 + wp * 32 + i * 16 + quad * 4;
        #pragma unroll
        for (int jq = 0; jq < 4; ++jq) {
            int cch = c0 + wq * 64 + jq * 16 + l15;
            float bz = bias[cch];
            float4 v;
            v.x = acc[i][jq][0] + bz;
            v.y = acc[i][jq][1] + bz;
            v.z = acc[i][jq][2] + bz;
            v.w = acc[i][jq][3] + bz;
            float* dst = out + ((size_t)b * CC + cch) * HW + pix;
            *(float4*)dst = v;
        }
    }
}

// ---------------- GEMM3 fallback (f32 w) ----------------
__global__ __launch_bounds__(256) void proj_gemm_kernel(const ushort_t* __restrict__ ao,
                                                        const float* __restrict__ w,
                                                        const float* __restrict__ bias,
                                                        float* __restrict__ out) {
    __shared__ __align__(16) ushort_t lds_p[64 * LP];
    __shared__ __align__(16) ushort_t lds_q[128 * LP];
    const int K = CC;
    int tid = threadIdx.x;
    int b = blockIdx.z;
    int p0 = blockIdx.x * 64;
    int c0 = blockIdx.y * 128;
    int lane = tid & 63, wv = tid >> 6;
    int wp = wv & 1, wq = wv >> 1;
    int quad = lane >> 4, l15 = lane & 15;

    f32x4 acc[2][4];
    #pragma unroll
    for (int i = 0; i < 2; ++i)
        #pragma unroll
        for (int jq = 0; jq < 4; ++jq) acc[i][jq] = (f32x4){0.f, 0.f, 0.f, 0.f};

    const ushort_t* abase = ao + ((size_t)b * HEADS) * HW * DD;

    for (int kt = 0; kt < K / 32; ++kt) {
        __syncthreads();
        {
            int row = tid >> 2, k8 = (tid & 3) * 8;
            uint4_t u = *(const uint4_t*)(abase + ((size_t)kt * HW + p0 + row) * DD + k8);
            *(uint4_t*)&lds_p[row * LP + k8] = u;
        }
        #pragma unroll
        for (int r = 0; r < 2; ++r) {
            int chunk = tid + r * 256;
            int row = chunk >> 2, k8 = (chunk & 3) * 8;
            const float* src = w + (size_t)(c0 + row) * K + kt * 32 + k8;
            float4 f0 = *(const float4*)src;
            float4 f1 = *(const float4*)(src + 4);
            uint4_t u;
            u[0] = pack2(f0.x, f0.y);
            u[1] = pack2(f0.z, f0.w);
            u[2] = pack2(f1.x, f1.y);
            u[3] = pack2(f1.z, f1.w);
            *(uint4_t*)&lds_q[row * LP + k8] = u;
        }
        __syncthreads();
        bf16x8 afrag[2], bfrag[4];
        #pragma unroll
        for (int i = 0; i < 2; ++i)
            afrag[i] = *(const bf16x8*)&lds_p[(wp * 32 + i * 16 + l15) * LP + quad * 8];
        #pragma unroll
        for (int jq = 0; jq < 4; ++jq)
            bfrag[jq] = *(const bf16x8*)&lds_q[(wq * 64 + jq * 16 + l15) * LP + quad * 8];
        #pragma unroll
        for (int i = 0; i < 2; ++i)
            #pragma unroll
            for (int jq = 0; jq < 4; ++jq)
                acc[i][jq] = __builtin_amdgcn_mfma_f32_16x16x32_bf16(afrag[i], bfrag[jq],
                                                                     acc[i][jq], 0, 0, 0);
    }
    #pragma unroll
    for (int i = 0; i < 2; ++i) {
        int pix = p0 + wp * 32 + i * 16 + quad * 4;
        #pragma unroll
        for (int jq = 0; jq < 4; ++jq) {
            int cch = c0 + wq * 64 + jq * 16 + l15;
            float bz = bias[cch];
            float4 v;
            v.x = acc[i][jq][0] + bz;
            v.y = acc[i][jq][1] + bz;
            v.z = acc[i][jq][2] + bz;
            v.w = acc[i][jq][3] + bz;
            float* dst = out + ((size_t)b * CC + cch) * HW + pix;
            *(float4*)dst = v;
        }
    }
}

extern "C" void kernel_launch(void* const* d_in, const int* in_sizes, int n_in,
                              void* d_out, int out_size, void* d_ws, size_t ws_size,
                              hipStream_t stream) {
    const float* x = (const float*)d_in[0];
    const float* qkv_w = (const float*)d_in[1];
    const float* rpb = (const float*)d_in[2];
    const float* proj_w = (const float*)d_in[3];
    const float* proj_b = (const float*)d_in[4];
    float* out = (float*)d_out;

    size_t need_min = 3 * PLANE * sizeof(ushort_t);                       // 73.5 MB
    size_t need_full = (4 * PLANE + WQ_ELEMS + WP_ELEMS) * sizeof(ushort_t);  // 100 MB

    if (ws_size < need_min) {
        zero_out_f32<<<dim3((int)((OUT_TOT + 255) / 256)), dim3(256), 0, stream>>>(out);
        return;
    }

    ushort_t* qkv = (ushort_t*)d_ws;                 // q/k/v: 3 bf16 planes

    if (ws_size >= need_full) {
        ushort_t* xbf = qkv + 3 * PLANE;             // bf16 x, [b][hw][c] (TRANSPOSED)
        ushort_t* wqb = qkv + 4 * PLANE;             // bf16 qkv_w
        ushort_t* wpb = wqb + WQ_ELEMS;              // bf16 proj_w

        xpose_cvt<<<dim3(49, 8, 8), dim3(256), 0, stream>>>(x, xbf);
        cvt_f32_bf16<<<dim3((WQ_ELEMS / 8 + 255) / 256), dim3(256), 0, stream>>>(
            qkv_w, wqb, WQ_ELEMS / 8);
        cvt_f32_bf16<<<dim3((WP_ELEMS / 8 + 255) / 256), dim3(256), 0, stream>>>(
            proj_w, wpb, WP_ELEMS / 8);

        qkv_gemm_bf16<<<dim3(49, 6, 8), dim3(256), 0, stream>>>(xbf, wqb, qkv);
        attn_mfma<<<dim3(49, HEADS, BATCH), dim3(256), 0, stream>>>(qkv, rpb);
        proj_gemm_bf16<<<dim3(49, 4, 8), dim3(256), 0, stream>>>(qkv, wpb, proj_b, out);
    } else {
        qkv_gemm_kernel<<<dim3(49, 12, 8), dim3(256), 0, stream>>>(x, qkv_w, qkv);
        attn_mfma<<<dim3(49, HEADS, BATCH), dim3(256), 0, stream>>>(qkv, rpb);
        proj_gemm_kernel<<<dim3(49, 4, 8), dim3(256), 0, stream>>>(qkv, proj_w, proj_b, out);
    }
}

// Round 8
// 255.239 us; speedup vs baseline: 1.9806x; 1.0306x over previous
//
#include <hip/hip_runtime.h>

// NeighborhoodAttention2D: B=8, C=512, H=W=56, heads=16, d=32, KSZ=7
// Round 16: 2-phase double-buffered GEMM staging (T3-minimum, plain HIP).
//  r15 post-mortem: conflicts 0, VALU 17% -> GEMM1 is barrier-drain latency-bound
//  (5 gload_lds drained by vmcnt(0) inside EVERY K-step's __syncthreads).
//  Fix: LDS dbuf; issue stage(t+1) BEFORE compute(t); ONE __syncthreads per tile
//  (its vmcnt(0) drain now overlaps the just-executed MFMA block).
//  Single-barrier dbuf correctness: buf[cur^1]'s readers (iter t-1) were fenced
//  by the previous barrier; end-of-body barrier fences these writes for t+1.
//  - applied to qkv_gemm_bf16 AND proj_gemm_bf16; attn/prep/fallbacks unchanged.

typedef unsigned short ushort_t;
typedef short bf16x8 __attribute__((ext_vector_type(8)));      // 8 bf16 = 4 VGPRs
typedef short bf16x4 __attribute__((ext_vector_type(4)));      // 4 bf16 = 2 VGPRs
typedef float f32x4 __attribute__((ext_vector_type(4)));       // MFMA C/D frag
typedef unsigned int uint4_t __attribute__((ext_vector_type(4)));
typedef unsigned int uint2_t __attribute__((ext_vector_type(2)));

#define BATCH 8
#define HEADS 16
#define HW 3136
#define HH 56
#define DD 32
#define CC 512
#define PLANE ((size_t)BATCH * HEADS * HW * DD)   // 12,845,056 elems (= B*C*HW)
#define OUT_TOT ((size_t)BATCH * CC * HW)
#define LP 40                                      // fallback-GEMM LDS pitch
#define LPG 32                                     // gload_lds GEMM pitch (linear rows)

// attention tile geometry
#define KT 14
#define KP 32
#define VPP 228

#define WQ_ELEMS (1536 * 512)
#define WP_ELEMS (512 * 512)

__device__ __forceinline__ ushort_t f2bf(float f) {
    union { float f; unsigned int i; } v; v.f = f;
    unsigned int r = v.i + 0x7FFFu + ((v.i >> 16) & 1u);   // RNE
    return (ushort_t)(r >> 16);
}
__device__ __forceinline__ unsigned int pack2(float a, float b) {
    return (unsigned int)f2bf(a) | ((unsigned int)f2bf(b) << 16);
}

__device__ __forceinline__ f32x4 mfma16x16x16(bf16x4 a, bf16x4 b, f32x4 c) {
#if __has_builtin(__builtin_amdgcn_mfma_f32_16x16x16bf16_1k)
    return __builtin_amdgcn_mfma_f32_16x16x16bf16_1k(a, b, c, 0, 0, 0);
#else
    f32x4 d;
    asm("v_mfma_f32_16x16x16_bf16 %0, %1, %2, %3" : "=v"(d) : "v"(a), "v"(b), "v"(c));
    return d;
#endif
}

// async global->LDS, 16B per lane; lds dest must be wave-linear (base + lane*16)
__device__ __forceinline__ void gload16(const ushort_t* g, ushort_t* l) {
    __builtin_amdgcn_global_load_lds(
        (const __attribute__((address_space(1))) unsigned int*)g,
        (__attribute__((address_space(3))) unsigned int*)l, 16, 0, 0);
}

__global__ __launch_bounds__(256) void zero_out_f32(float* __restrict__ out) {
    size_t idx = (size_t)blockIdx.x * 256 + threadIdx.x;
    if (idx < OUT_TOT) out[idx] = 0.f;
}

// ---------------- prep: f32 -> bf16 linear (weights) ----------------
__global__ __launch_bounds__(256) void cvt_f32_bf16(const float* __restrict__ src,
                                                    ushort_t* __restrict__ dst, int n8) {
    int idx = blockIdx.x * 256 + threadIdx.x;
    if (idx >= n8) return;
    const float4* s = (const float4*)src + (size_t)idx * 2;
    float4 f0 = s[0], f1 = s[1];
    uint4_t u;
    u[0] = pack2(f0.x, f0.y);
    u[1] = pack2(f0.z, f0.w);
    u[2] = pack2(f1.x, f1.y);
    u[3] = pack2(f1.z, f1.w);
    *(uint4_t*)(dst + (size_t)idx * 8) = u;
}

// ---------------- prep: x [b][c][hw] f32 -> xbf [b][hw][c] bf16 ----------------
__global__ __launch_bounds__(256) void xpose_cvt(const float* __restrict__ x,
                                                 ushort_t* __restrict__ xb) {
    __shared__ ushort_t T[64 * 64];                // 8192 B
    int tid = threadIdx.x;
    int hw0 = blockIdx.x * 64;
    int c0 = blockIdx.y * 64;
    int b = blockIdx.z;

    int cr = tid >> 2, hq = tid & 3;
    const float* src = x + ((size_t)b * CC + c0 + cr) * HW + hw0 + hq * 16;
    float4 f0 = *(const float4*)(src);
    float4 f1 = *(const float4*)(src + 4);
    float4 f2 = *(const float4*)(src + 8);
    float4 f3 = *(const float4*)(src + 12);
    uint4_t u0, u1;
    u0[0] = pack2(f0.x, f0.y); u0[1] = pack2(f0.z, f0.w);
    u0[2] = pack2(f1.x, f1.y); u0[3] = pack2(f1.z, f1.w);
    u1[0] = pack2(f2.x, f2.y); u1[1] = pack2(f2.z, f2.w);
    u1[2] = pack2(f3.x, f3.y); u1[3] = pack2(f3.z, f3.w);
    int sw = ((cr >> 4) & 3) << 4;
    int col0 = (hq * 16) ^ sw;
    *(uint4_t*)&T[cr * 64 + col0] = u0;
    *(uint4_t*)&T[cr * 64 + col0 + 8] = u1;

    __syncthreads();

    int p = tid >> 2, cq = tid & 3;
    int pc = p ^ (cq << 4);
    unsigned vv[8];
    #pragma unroll
    for (int j = 0; j < 16; j += 2) {
        unsigned a = T[(cq * 16 + j) * 64 + pc];
        unsigned b2 = T[(cq * 16 + j + 1) * 64 + pc];
        vv[j >> 1] = a | (b2 << 16);
    }
    ushort_t* dst = xb + ((size_t)b * HW + hw0 + p) * CC + c0 + cq * 16;
    uint4_t w0, w1;
    w0[0] = vv[0]; w0[1] = vv[1]; w0[2] = vv[2]; w0[3] = vv[3];
    w1[0] = vv[4]; w1[1] = vv[5]; w1[2] = vv[6]; w1[3] = vv[7];
    *(uint4_t*)&dst[0] = w0;
    *(uint4_t*)&dst[8] = w1;
}

// ---------------- GEMM1 (bf16): qkv^T = wq (1536x512) . xb ([b][hw][c]) ----------
// 2-phase dbuf gload_lds staging; swizzle ch^=(row>>1)&3 on source + frag read.
__global__ __launch_bounds__(256) void qkv_gemm_bf16(const ushort_t* __restrict__ xb,
                                                     const ushort_t* __restrict__ w,
                                                     ushort_t* __restrict__ qkv) {
    __shared__ __align__(16) ushort_t lds_p[2][256 * LPG];   // 2 x 16384 B
    __shared__ __align__(16) ushort_t lds_q[2][64 * LPG];    // 2 x  4096 B
    int tid = threadIdx.x;
    int b = blockIdx.z;
    int n0 = blockIdx.y * 256;
    int p0 = blockIdx.x * 64;
    int lane = tid & 63, wv = tid >> 6;
    int wp = wv & 1, wq = wv >> 1;
    int quad = lane >> 4, l15 = lane & 15;

    f32x4 acc[8][2];
    #pragma unroll
    for (int i = 0; i < 8; ++i)
        #pragma unroll
        for (int jq = 0; jq < 2; ++jq) acc[i][jq] = (f32x4){0.f, 0.f, 0.f, 0.f};

    int swz = (l15 >> 1) & 3;                  // fragment-read swizzle (row->chunk)
    int cha = (quad ^ swz) * 8;                // swizzled k-octet for frag reads

    // per-thread staging descriptors (constant across kt)
    int ca_row[4], ca_k8[4];
    #pragma unroll
    for (int r = 0; r < 4; ++r) {
        int c = r * 256 + tid;
        ca_row[r] = c >> 2;
        ca_k8[r] = ((c & 3) ^ ((c >> 3) & 3)) * 8;
    }
    int cb_row = tid >> 2;
    int cb_k8 = ((tid & 3) ^ ((tid >> 3) & 3)) * 8;

    const int NKT = CC / 32;
    // prologue: stage tile 0 into buffer 0
    #pragma unroll
    for (int r = 0; r < 4; ++r)
        gload16(w + (size_t)(n0 + ca_row[r]) * CC + ca_k8[r], &lds_p[0][(r * 256 + tid) * 8]);
    gload16(xb + ((size_t)b * HW + p0 + cb_row) * CC + cb_k8, &lds_q[0][tid * 8]);
    __syncthreads();

    for (int kt = 0; kt < NKT; ++kt) {
        int cur = kt & 1;
        if (kt + 1 < NKT) {                    // stage NEXT tile first (overlap)
            int ko = (kt + 1) * 32;
            #pragma unroll
            for (int r = 0; r < 4; ++r)
                gload16(w + (size_t)(n0 + ca_row[r]) * CC + ko + ca_k8[r],
                        &lds_p[cur ^ 1][(r * 256 + tid) * 8]);
            gload16(xb + ((size_t)b * HW + p0 + cb_row) * CC + ko + cb_k8,
                    &lds_q[cur ^ 1][tid * 8]);
        }
        bf16x8 afrag[8], bfrag[2];
        #pragma unroll
        for (int i = 0; i < 8; ++i)
            afrag[i] = *(const bf16x8*)&lds_p[cur][(wp * 128 + i * 16 + l15) * LPG + cha];
        #pragma unroll
        for (int jq = 0; jq < 2; ++jq)
            bfrag[jq] = *(const bf16x8*)&lds_q[cur][(wq * 32 + jq * 16 + l15) * LPG + cha];
        #pragma unroll
        for (int i = 0; i < 8; ++i)
            #pragma unroll
            for (int jq = 0; jq < 2; ++jq)
                acc[i][jq] = __builtin_amdgcn_mfma_f32_16x16x32_bf16(afrag[i], bfrag[jq],
                                                                     acc[i][jq], 0, 0, 0);
        __syncthreads();                       // vmcnt(0) drain overlapped by MFMAs above
    }
    const float qscale = 0.17677669529663687f;   // 1/sqrt(32)
    #pragma unroll
    for (int i = 0; i < 8; ++i) {
        int nbase = n0 + wp * 128 + i * 16 + quad * 4;
        int which = nbase >> 9;
        int h = (nbase >> 5) & 15;
        int dch = nbase & 31;
        float sc = (which == 0) ? qscale : 1.0f;
        #pragma unroll
        for (int jq = 0; jq < 2; ++jq) {
            int pix = p0 + wq * 32 + jq * 16 + l15;
            uint2_t v;
            v[0] = pack2(acc[i][jq][0] * sc, acc[i][jq][1] * sc);
            v[1] = pack2(acc[i][jq][2] * sc, acc[i][jq][3] * sc);
            ushort_t* dst = qkv + (size_t)which * PLANE +
                            ((((size_t)b * HEADS + h) * HW + pix) * DD + dch);
            *(uint2_t*)dst = v;
        }
    }
}

// ---------------- GEMM1 fallback (f32 inputs) ----------------
__global__ __launch_bounds__(256) void qkv_gemm_kernel(const float* __restrict__ x,
                                                       const float* __restrict__ w,
                                                       ushort_t* __restrict__ qkv) {
    __shared__ __align__(16) ushort_t lds_p[128 * LP];
    __shared__ __align__(16) ushort_t lds_q[64 * LP];
    const int K = CC;
    int tid = threadIdx.x;
    int b = blockIdx.z;
    int n0 = blockIdx.y * 128;
    int p0 = blockIdx.x * 64;
    int lane = tid & 63, wv = tid >> 6;
    int wp = wv & 1, wq = wv >> 1;
    int quad = lane >> 4, l15 = lane & 15;

    f32x4 acc[4][2];
    #pragma unroll
    for (int i = 0; i < 4; ++i)
        #pragma unroll
        for (int jq = 0; jq < 2; ++jq) acc[i][jq] = (f32x4){0.f, 0.f, 0.f, 0.f};

    int spx = tid & 63;
    int sk8 = (tid >> 6) * 8;

    for (int kt = 0; kt < K / 32; ++kt) {
        __syncthreads();
        #pragma unroll
        for (int r = 0; r < 2; ++r) {
            int chunk = tid + r * 256;
            int row = chunk >> 2, k8 = (chunk & 3) * 8;
            const float* src = w + (size_t)(n0 + row) * K + kt * 32 + k8;
            float4 f0 = *(const float4*)src;
            float4 f1 = *(const float4*)(src + 4);
            uint4_t u;
            u[0] = pack2(f0.x, f0.y);
            u[1] = pack2(f0.z, f0.w);
            u[2] = pack2(f1.x, f1.y);
            u[3] = pack2(f1.z, f1.w);
            *(uint4_t*)&lds_p[row * LP + k8] = u;
        }
        {
            const float* xcol = x + ((size_t)b * CC + kt * 32 + sk8) * HW + p0 + spx;
            float v0 = xcol[0];
            float v1 = xcol[(size_t)HW];
            float v2 = xcol[(size_t)2 * HW];
            float v3 = xcol[(size_t)3 * HW];
            float v4 = xcol[(size_t)4 * HW];
            float v5 = xcol[(size_t)5 * HW];
            float v6 = xcol[(size_t)6 * HW];
            float v7 = xcol[(size_t)7 * HW];
            uint4_t u;
            u[0] = pack2(v0, v1);
            u[1] = pack2(v2, v3);
            u[2] = pack2(v4, v5);
            u[3] = pack2(v6, v7);
            *(uint4_t*)&lds_q[spx * LP + sk8] = u;
        }
        __syncthreads();
        bf16x8 afrag[4], bfrag[2];
        #pragma unroll
        for (int i = 0; i < 4; ++i)
            afrag[i] = *(const bf16x8*)&lds_p[(wp * 64 + i * 16 + l15) * LP + quad * 8];
        #pragma unroll
        for (int jq = 0; jq < 2; ++jq)
            bfrag[jq] = *(const bf16x8*)&lds_q[(wq * 32 + jq * 16 + l15) * LP + quad * 8];
        #pragma unroll
        for (int i = 0; i < 4; ++i)
            #pragma unroll
            for (int jq = 0; jq < 2; ++jq)
                acc[i][jq] = __builtin_amdgcn_mfma_f32_16x16x32_bf16(afrag[i], bfrag[jq],
                                                                     acc[i][jq], 0, 0, 0);
    }
    const float qscale = 0.17677669529663687f;
    #pragma unroll
    for (int i = 0; i < 4; ++i) {
        int nbase = n0 + wp * 64 + i * 16 + quad * 4;
        int which = nbase >> 9;
        int h = (nbase >> 5) & 15;
        int dch = nbase & 31;
        float sc = (which == 0) ? qscale : 1.0f;
        #pragma unroll
        for (int jq = 0; jq < 2; ++jq) {
            int pix = p0 + wq * 32 + jq * 16 + l15;
            uint2_t v;
            v[0] = pack2(acc[i][jq][0] * sc, acc[i][jq][1] * sc);
            v[1] = pack2(acc[i][jq][2] * sc, acc[i][jq][3] * sc);
            ushort_t* dst = qkv + (size_t)which * PLANE +
                            ((((size_t)b * HEADS + h) * HW + pix) * DD + dch);
            *(uint2_t*)dst = v;
        }
    }
}

// ---------------- MFMA attention: one block per (b, h, 8x8 query tile) ----------------
__global__ __launch_bounds__(256, 4) void attn_mfma(ushort_t* __restrict__ qkv,
                                                    const float* __restrict__ rpb) {
    __shared__ __align__(16) ushort_t Klds[224 * KP];        // 14336 B, [kk][d]
    __shared__ __align__(16) ushort_t Vlds[DD * VPP];        // 14592 B, [d][kk]
    __shared__ float rpbl[169];                              //   676 B

    int tid = threadIdx.x;
    int b = blockIdx.z, h = blockIdx.y;
    int tile = blockIdx.x;
    int ti = tile / 7, tj = tile - ti * 7;
    int i0 = ti * 8, j0 = tj * 8;
    int kr0 = min(max(i0 - 3, 0), HH - 14);
    int kc0 = min(max(j0 - 3, 0), HH - 14);

    const ushort_t* qp = qkv + (((size_t)b * HEADS + h) * HW) * DD;
    const ushort_t* kp = qp + PLANE;
    const ushort_t* vp = qp + 2 * PLANE;

    if (tid < 169) rpbl[tid] = rpb[h * 169 + tid];

    #pragma unroll
    for (int r = 0; r < 4; ++r) {
        int idx = tid + r * 256;
        if (idx < 784) {
            int u = idx / 56;
            int rem = idx - u * 56;
            int w = rem >> 2, d8 = (rem & 3) << 3;
            const ushort_t* src = kp + ((size_t)((kr0 + u) * HH + kc0 + w)) * DD + d8;
            *(uint4_t*)&Klds[(u * 16 + w) * KP + d8] = *(const uint4_t*)src;
        } else if (idx < 896) {
            int z = idx - 784;
            int u = z >> 3, rem = z & 7;
            int w = 14 + (rem >> 2), d8 = (rem & 3) << 3;
            *(uint4_t*)&Klds[(u * 16 + w) * KP + d8] = (uint4_t){0, 0, 0, 0};
        }
    }
    #pragma unroll
    for (int rr = 0; rr < 2; ++rr) {
        int idx = tid + rr * 256;
        if (idx < 448) {
            int u = idx >> 5, rem = idx & 31;
            int pr = rem >> 2, d8 = (rem & 3) << 3;
            int kk0 = u * 16 + pr * 2;
            if (pr < 7) {
                const ushort_t* s0 = vp + ((size_t)((kr0 + u) * HH + kc0 + pr * 2)) * DD + d8;
                uint4_t a = *(const uint4_t*)s0;
                uint4_t c = *(const uint4_t*)(s0 + DD);
                #pragma unroll
                for (int e = 0; e < 4; ++e) {
                    unsigned lo = (a[e] & 0xFFFFu) | (c[e] << 16);
                    unsigned hi = (a[e] >> 16) | (c[e] & 0xFFFF0000u);
                    *(unsigned*)&Vlds[(d8 + 2 * e) * VPP + kk0] = lo;
                    *(unsigned*)&Vlds[(d8 + 2 * e + 1) * VPP + kk0] = hi;
                }
            } else {
                #pragma unroll
                for (int e = 0; e < 8; ++e)
                    *(unsigned*)&Vlds[(d8 + e) * VPP + kk0] = 0;
            }
        }
    }

    int lane = tid & 63, wv = tid >> 6;
    int l15 = lane & 15, quad = lane >> 4;
    int q_idx = wv * 16 + l15;
    int qi = i0 + (q_idx >> 3), qj = j0 + (q_idx & 7);
    int si = min(max(qi - 3, 0), HH - 7);
    int sj = min(max(qj - 3, 0), HH - 7);

    bf16x8 bq = *(const bf16x8*)(qp + ((size_t)(qi * HH + qj)) * DD + quad * 8);

    int jbase = kc0 + quad * 4 - sj;
    int cbase = kc0 + quad * 4 - qj + 6;
    int coff[4];
    bool cok[4];
    #pragma unroll
    for (int r2 = 0; r2 < 4; ++r2) {
        cok[r2] = (unsigned)(jbase + r2) <= 6u;
        coff[r2] = min(max(cbase + r2, 0), 12);
    }

    __syncthreads();

    f32x4 lg[KT];
    f32x4 zf = {0.f, 0.f, 0.f, 0.f};
    #pragma unroll
    for (int t = 0; t < KT; ++t) {
        bf16x8 ak = *(const bf16x8*)&Klds[(t * 16 + l15) * KP + quad * 8];
        lg[t] = __builtin_amdgcn_mfma_f32_16x16x32_bf16(ak, bq, zf, 0, 0, 0);
    }

    int abase = kr0 - qi + 6;
    #pragma unroll
    for (int t = 0; t < KT; ++t) {
        bool rok = (unsigned)(kr0 + t - si) <= 6u;
        int arow = min(max(abase + t, 0), 12);
        const float* br = &rpbl[arow * 13];
        #pragma unroll
        for (int r2 = 0; r2 < 4; ++r2) {
            float bias = br[coff[r2]];
            lg[t][r2] = (rok && cok[r2]) ? lg[t][r2] + bias : -1e30f;
        }
    }

    float m = -1e30f;
    #pragma unroll
    for (int t = 0; t < KT; ++t)
        #pragma unroll
        for (int r2 = 0; r2 < 4; ++r2) m = fmaxf(m, lg[t][r2]);
    m = fmaxf(m, __shfl_xor(m, 16));
    m = fmaxf(m, __shfl_xor(m, 32));
    float s = 0.f;
    #pragma unroll
    for (int t = 0; t < KT; ++t)
        #pragma unroll
        for (int r2 = 0; r2 < 4; ++r2) {
            float e = __expf(lg[t][r2] - m);
            lg[t][r2] = e;
            s += e;
        }
    s += __shfl_xor(s, 16);
    s += __shfl_xor(s, 32);
    float inv = 1.f / s;

    bf16x4 pb[KT];
    #pragma unroll
    for (int t = 0; t < KT; ++t) {
        union { uint2_t u; bf16x4 v; } cv;
        cv.u[0] = pack2(lg[t][0], lg[t][1]);
        cv.u[1] = pack2(lg[t][2], lg[t][3]);
        pb[t] = cv.v;
    }

    f32x4 acc0 = zf, acc1 = zf;
    #pragma unroll
    for (int t = 0; t < KT; ++t) {
        bf16x4 bv0 = *(const bf16x4*)&Vlds[l15 * VPP + t * 16 + quad * 4];
        bf16x4 bv1 = *(const bf16x4*)&Vlds[(16 + l15) * VPP + t * 16 + quad * 4];
        acc0 = mfma16x16x16(pb[t], bv0, acc0);
        acc1 = mfma16x16x16(pb[t], bv1, acc1);
    }

    ushort_t* op = qkv + (((size_t)b * HEADS + h) * HW) * DD;
    #pragma unroll
    for (int e = 0; e < 4; ++e) {
        float invq = __shfl(inv, quad * 4 + e);
        int q2 = wv * 16 + quad * 4 + e;
        int pix = (i0 + (q2 >> 3)) * HH + j0 + (q2 & 7);
        op[(size_t)pix * DD + l15] = f2bf(acc0[e] * invq);
        op[(size_t)pix * DD + 16 + l15] = f2bf(acc1[e] * invq);
    }
}

// ---------------- GEMM3 (bf16): y = attn_out . wpb^T + b; OUT f32 ----------------
// 2-phase dbuf gload_lds staging; swizzled source + swizzled frag reads.
__global__ __launch_bounds__(256) void proj_gemm_bf16(const ushort_t* __restrict__ ao,
                                                      const ushort_t* __restrict__ w,
                                                      const float* __restrict__ bias,
                                                      float* __restrict__ out) {
    __shared__ __align__(16) ushort_t lds_p[2][64 * LPG];    // 2 x 4096 B
    __shared__ __align__(16) ushort_t lds_q[2][128 * LPG];   // 2 x 8192 B
    int tid = threadIdx.x;
    int b = blockIdx.z;
    int p0 = blockIdx.x * 64;
    int c0 = blockIdx.y * 128;
    int lane = tid & 63, wv = tid >> 6;
    int wp = wv & 1, wq = wv >> 1;
    int quad = lane >> 4, l15 = lane & 15;

    f32x4 acc[2][4];
    #pragma unroll
    for (int i = 0; i < 2; ++i)
        #pragma unroll
        for (int jq = 0; jq < 4; ++jq) acc[i][jq] = (f32x4){0.f, 0.f, 0.f, 0.f};

    const ushort_t* abase = ao + ((size_t)b * HEADS) * HW * DD;
    int swz = (l15 >> 1) & 3;
    int cha = (quad ^ swz) * 8;

    int ca_row = tid >> 2;
    int ca_k8 = ((tid & 3) ^ ((tid >> 3) & 3)) * 8;
    int cb_row[2], cb_k8[2];
    #pragma unroll
    for (int r = 0; r < 2; ++r) {
        int c = r * 256 + tid;
        cb_row[r] = c >> 2;
        cb_k8[r] = ((c & 3) ^ ((c >> 3) & 3)) * 8;
    }

    const int NKT = CC / 32;
    // prologue: stage tile 0 into buffer 0 (A k-tile 0 = head 0)
    gload16(abase + ((size_t)0 * HW + p0 + ca_row) * DD + ca_k8, &lds_p[0][tid * 8]);
    #pragma unroll
    for (int r = 0; r < 2; ++r)
        gload16(w + (size_t)(c0 + cb_row[r]) * CC + cb_k8[r],
                &lds_q[0][(r * 256 + tid) * 8]);
    __syncthreads();

    for (int kt = 0; kt < NKT; ++kt) {
        int cur = kt & 1;
        if (kt + 1 < NKT) {                    // stage NEXT tile first (overlap)
            int kn = kt + 1;
            gload16(abase + ((size_t)kn * HW + p0 + ca_row) * DD + ca_k8,
                    &lds_p[cur ^ 1][tid * 8]);
            #pragma unroll
            for (int r = 0; r < 2; ++r)
                gload16(w + (size_t)(c0 + cb_row[r]) * CC + kn * 32 + cb_k8[r],
                        &lds_q[cur ^ 1][(r * 256 + tid) * 8]);
        }
        bf16x8 afrag[2], bfrag[4];
        #pragma unroll
        for (int i = 0; i < 2; ++i)
            afrag[i] = *(const bf16x8*)&lds_p[cur][(wp * 32 + i * 16 + l15) * LPG + cha];
        #pragma unroll
        for (int jq = 0; jq < 4; ++jq)
            bfrag[jq] = *(const bf16x8*)&lds_q[cur][(wq * 64 + jq * 16 + l15) * LPG + cha];
        #pragma unroll
        for (int i = 0; i < 2; ++i)
            #pragma unroll
            for (int jq = 0; jq < 4; ++jq)
                acc[i][jq] = __builtin_amdgcn_mfma_f32_16x16x32_bf16(afrag[i], bfrag[jq],
                                                                     acc[i][jq], 0, 0, 0);
        __syncthreads();
    }
    #pragma unroll
    for (int i = 0; i < 2; ++i) {
        int pix = p0 + wp * 32 + i * 16 + quad * 4;
        #pragma unroll
        for (int jq = 0; jq < 4; ++jq) {
            int cch = c0 + wq * 64 + jq * 16 + l15;
            float bz = bias[cch];
            float4 v;
            v.x = acc[i][jq][0] + bz;
            v.y = acc[i][jq][1] + bz;
            v.z = acc[i][jq][2] + bz;
            v.w = acc[i][jq][3] + bz;
            float* dst = out + ((size_t)b * CC + cch) * HW + pix;
            *(float4*)dst = v;
        }
    }
}

// ---------------- GEMM3 fallback (f32 w) ----------------
__global__ __launch_bounds__(256) void proj_gemm_kernel(const ushort_t* __restrict__ ao,
                                                        const float* __restrict__ w,
                                                        const float* __restrict__ bias,
                                                        float* __restrict__ out) {
    __shared__ __align__(16) ushort_t lds_p[64 * LP];
    __shared__ __align__(16) ushort_t lds_q[128 * LP];
    const int K = CC;
    int tid = threadIdx.x;
    int b = blockIdx.z;
    int p0 = blockIdx.x * 64;
    int c0 = blockIdx.y * 128;
    int lane = tid & 63, wv = tid >> 6;
    int wp = wv & 1, wq = wv >> 1;
    int quad = lane >> 4, l15 = lane & 15;

    f32x4 acc[2][4];
    #pragma unroll
    for (int i = 0; i < 2; ++i)
        #pragma unroll
        for (int jq = 0; jq < 4; ++jq) acc[i][jq] = (f32x4){0.f, 0.f, 0.f, 0.f};

    const ushort_t* abase = ao + ((size_t)b * HEADS) * HW * DD;

    for (int kt = 0; kt < K / 32; ++kt) {
        __syncthreads();
        {
            int row = tid >> 2, k8 = (tid & 3) * 8;
            uint4_t u = *(const uint4_t*)(abase + ((size_t)kt * HW + p0 + row) * DD + k8);
            *(uint4_t*)&lds_p[row * LP + k8] = u;
        }
        #pragma unroll
        for (int r = 0; r < 2; ++r) {
            int chunk = tid + r * 256;
            int row = chunk >> 2, k8 = (chunk & 3) * 8;
            const float* src = w + (size_t)(c0 + row) * K + kt * 32 + k8;
            float4 f0 = *(const float4*)src;
            float4 f1 = *(const float4*)(src + 4);
            uint4_t u;
            u[0] = pack2(f0.x, f0.y);
            u[1] = pack2(f0.z, f0.w);
            u[2] = pack2(f1.x, f1.y);
            u[3] = pack2(f1.z, f1.w);
            *(uint4_t*)&lds_q[row * LP + k8] = u;
        }
        __syncthreads();
        bf16x8 afrag[2], bfrag[4];
        #pragma unroll
        for (int i = 0; i < 2; ++i)
            afrag[i] = *(const bf16x8*)&lds_p[(wp * 32 + i * 16 + l15) * LP + quad * 8];
        #pragma unroll
        for (int jq = 0; jq < 4; ++jq)
            bfrag[jq] = *(const bf16x8*)&lds_q[(wq * 64 + jq * 16 + l15) * LP + quad * 8];
        #pragma unroll
        for (int i = 0; i < 2; ++i)
            #pragma unroll
            for (int jq = 0; jq < 4; ++jq)
                acc[i][jq] = __builtin_amdgcn_mfma_f32_16x16x32_bf16(afrag[i], bfrag[jq],
                                                                     acc[i][jq], 0, 0, 0);
    }
    #pragma unroll
    for (int i = 0; i < 2; ++i) {
        int pix = p0 + wp * 32 + i * 16 + quad * 4;
        #pragma unroll
        for (int jq = 0; jq < 4; ++jq) {
            int cch = c0 + wq * 64 + jq * 16 + l15;
            float bz = bias[cch];
            float4 v;
            v.x = acc[i][jq][0] + bz;
            v.y = acc[i][jq][1] + bz;
            v.z = acc[i][jq][2] + bz;
            v.w = acc[i][jq][3] + bz;
            float* dst = out + ((size_t)b * CC + cch) * HW + pix;
            *(float4*)dst = v;
        }
    }
}

extern "C" void kernel_launch(void* const* d_in, const int* in_sizes, int n_in,
                              void* d_out, int out_size, void* d_ws, size_t ws_size,
                              hipStream_t stream) {
    const float* x = (const float*)d_in[0];
    const float* qkv_w = (const float*)d_in[1];
    const float* rpb = (const float*)d_in[2];
    const float* proj_w = (const float*)d_in[3];
    const float* proj_b = (const float*)d_in[4];
    float* out = (float*)d_out;

    size_t need_min = 3 * PLANE * sizeof(ushort_t);                       // 73.5 MB
    size_t need_full = (4 * PLANE + WQ_ELEMS + WP_ELEMS) * sizeof(ushort_t);  // 100 MB

    if (ws_size < need_min) {
        zero_out_f32<<<dim3((int)((OUT_TOT + 255) / 256)), dim3(256), 0, stream>>>(out);
        return;
    }

    ushort_t* qkv = (ushort_t*)d_ws;                 // q/k/v: 3 bf16 planes

    if (ws_size >= need_full) {
        ushort_t* xbf = qkv + 3 * PLANE;             // bf16 x, [b][hw][c] (TRANSPOSED)
        ushort_t* wqb = qkv + 4 * PLANE;             // bf16 qkv_w
        ushort_t* wpb = wqb + WQ_ELEMS;              // bf16 proj_w

        xpose_cvt<<<dim3(49, 8, 8), dim3(256), 0, stream>>>(x, xbf);
        cvt_f32_bf16<<<dim3((WQ_ELEMS / 8 + 255) / 256), dim3(256), 0, stream>>>(
            qkv_w, wqb, WQ_ELEMS / 8);
        cvt_f32_bf16<<<dim3((WP_ELEMS / 8 + 255) / 256), dim3(256), 0, stream>>>(
            proj_w, wpb, WP_ELEMS / 8);

        qkv_gemm_bf16<<<dim3(49, 6, 8), dim3(256), 0, stream>>>(xbf, wqb, qkv);
        attn_mfma<<<dim3(49, HEADS, BATCH), dim3(256), 0, stream>>>(qkv, rpb);
        proj_gemm_bf16<<<dim3(49, 4, 8), dim3(256), 0, stream>>>(qkv, wpb, proj_b, out);
    } else {
        qkv_gemm_kernel<<<dim3(49, 12, 8), dim3(256), 0, stream>>>(x, qkv_w, qkv);
        attn_mfma<<<dim3(49, HEADS, BATCH), dim3(256), 0, stream>>>(qkv, rpb);
        proj_gemm_kernel<<<dim3(49, 4, 8), dim3(256), 0, stream>>>(qkv, proj_w, proj_b, out);
    }
}